// Round 6
// baseline (343.549 us; speedup 1.0000x reference)
//
#include <hip/hip_runtime.h>
#include <hip/hip_cooperative_groups.h>
#include <stdint.h>

namespace cg = cooperative_groups;

#define DH 128   // D_IN == H == 128
#define NB 30    // num bases
#define NR 8     // num relations

typedef short bf16x8 __attribute__((ext_vector_type(8)));   // 8 bf16 = 4 VGPRs
typedef float f32x4 __attribute__((ext_vector_type(4)));
typedef float f32x2 __attribute__((ext_vector_type(2)));

static __device__ __forceinline__ unsigned short f2bf(float f) {
    unsigned u = __float_as_uint(f);
    u += 0x7fffu + ((u >> 16) & 1u);   // round-to-nearest-even
    return (unsigned short)(u >> 16);
}
static __device__ __forceinline__ float bflo(unsigned u) { return __uint_as_float(u << 16); }
static __device__ __forceinline__ float bfhi(unsigned u) { return __uint_as_float(u & 0xffff0000u); }

// ---------- weight prep (transposed bf16) ----------
__global__ __launch_bounds__(128) void k_wprep(const float* __restrict__ comp,
                                               const float* __restrict__ basis,
                                               const float* __restrict__ root,
                                               const float* __restrict__ wrel,
                                               const float* __restrict__ wroot2,
                                               unsigned short* __restrict__ wallT,
                                               unsigned short* __restrict__ WT2) {
    int o = threadIdx.x;    // 0..127
    int i = blockIdx.x;     // 0..127
    int y = blockIdx.y;     // 0..10
    if (y < NR) {
        float s = 0.f;
        #pragma unroll
        for (int b = 0; b < NB; ++b)
            s += comp[y * NB + b] * basis[((size_t)b * DH + i) * DH + o];
        wallT[((size_t)y * DH + o) * DH + i] = f2bf(s);
    } else if (y == NR) {
        wallT[((size_t)NR * DH + o) * DH + i] = f2bf(root[i * DH + o]);
    } else {
        const float* W = (y == NR + 2) ? wroot2 : wrel;
        WT2[((size_t)(y - NR - 1) * DH + o) * DH + i] = f2bf(W[i * DH + o]);
    }
}

// ---------- fused CSR build (cooperative): hist -> scan -> scatter ----------
// grid 40 x 1024. deg & cursor must be pre-zeroed.
__global__ __launch_bounds__(1024) void k_csr(const int* __restrict__ src,
                                              const int* __restrict__ dstA,
                                              const int* __restrict__ etype, int E,
                                              int* __restrict__ deg,
                                              int* __restrict__ offsets,
                                              int* __restrict__ partial,
                                              int* __restrict__ cursor,
                                              unsigned* __restrict__ sorted, int n) {
    cg::grid_group grid = cg::this_grid();
    __shared__ int s[1024];
    __shared__ int pre_s;
    const int tid = threadIdx.x;
    const int b = blockIdx.x;
    const int T = gridDim.x * 1024;
    const int gtid = b * 1024 + tid;

    // phase 1: histogram
    for (int e = gtid; e < E; e += T) atomicAdd(&deg[dstA[e]], 1);
    grid.sync();

    // phase 2: per-block inclusive scan -> exclusive offsets + block totals
    int i = b * 1024 + tid;
    int v = (i < n) ? deg[i] : 0;
    s[tid] = v;
    __syncthreads();
    for (int off = 1; off < 1024; off <<= 1) {
        int t = (tid >= off) ? s[tid - off] : 0;
        __syncthreads();
        s[tid] += t;
        __syncthreads();
    }
    if (i <= n) offsets[i] = s[tid] - v;   // exclusive
    if (tid == 1023) partial[b] = s[1023];
    grid.sync();

    // phase 3: add prefix of block totals
    if (tid == 0) {
        int pre = 0;
        for (int t = 0; t < b; ++t) pre += partial[t];
        pre_s = pre;
    }
    __syncthreads();
    if (i <= n) offsets[i] += pre_s;
    grid.sync();

    // phase 4: scatter edges into CSR order
    for (int e = gtid; e < E; e += T) {
        int d = dstA[e];
        int pos = offsets[d] + atomicAdd(&cursor[d], 1);
        sorted[pos] = (unsigned)src[e] | ((unsigned)etype[e] << 17);  // src<2^17, type<8
    }
}

// ---------- MFMA GEMM1: 128x128 tile, K=128, grid (ceil(N/128), 3) ----------
// Stages fp32 X -> bf16 LDS directly (cvtx folded in).
// blockIdx.y=g handles relations r = 3g..3g+2.
// r<8: xw8[r] = fp8(X @ W_r). r==8: hb = bf16(X @ root + bias1)
__global__ __launch_bounds__(256) void k_gemm1m(const float* __restrict__ x,
                                                const unsigned short* __restrict__ wallT,
                                                const float* __restrict__ bias1,
                                                int Nn,
                                                unsigned* __restrict__ xw8,
                                                unsigned short* __restrict__ hb) {
    __shared__ __align__(16) unsigned short As[128][136];  // [m][k], +8 pad
    __shared__ __align__(16) unsigned short Bs[128][136];  // [n][k] / epilogue repack
    const int tid = threadIdx.x;
    const int wave = tid >> 6, lane = tid & 63;
    const int g = blockIdx.y;
    const int rowbase = blockIdx.x * 128;
    const int lq = lane >> 4, lr = lane & 15;

    // stage A once: fp32 -> bf16 on the fly
    #pragma unroll
    for (int it = 0; it < 8; ++it) {
        int c = it * 256 + tid;
        int row = c >> 4, col = c & 15;
        int rg = rowbase + row; if (rg >= Nn) rg = Nn - 1;
        float4 v0 = *(const float4*)&x[(size_t)rg * DH + col * 8];
        float4 v1 = *(const float4*)&x[(size_t)rg * DH + col * 8 + 4];
        uint4 u;
        u.x = (unsigned)f2bf(v0.x) | ((unsigned)f2bf(v0.y) << 16);
        u.y = (unsigned)f2bf(v0.z) | ((unsigned)f2bf(v0.w) << 16);
        u.z = (unsigned)f2bf(v1.x) | ((unsigned)f2bf(v1.y) << 16);
        u.w = (unsigned)f2bf(v1.z) | ((unsigned)f2bf(v1.w) << 16);
        *(uint4*)&As[row][col * 8] = u;
    }

    for (int rr = 0; rr < 3; ++rr) {
        const int r = g * 3 + rr;
        const unsigned short* WT = wallT + (size_t)r * DH * DH;
        if (rr) __syncthreads();            // prior epilogue reads of Bs done
        #pragma unroll
        for (int it = 0; it < 8; ++it) {
            int c = it * 256 + tid;
            int row = c >> 4, col = c & 15;
            *(uint4*)&Bs[row][col * 8] = *(const uint4*)&WT[(size_t)row * DH + col * 8];
        }
        __syncthreads();                    // also covers As on first iter

        f32x4 acc[2][8];
        #pragma unroll
        for (int mt = 0; mt < 2; ++mt)
            #pragma unroll
            for (int nt = 0; nt < 8; ++nt) acc[mt][nt] = (f32x4)0.f;

        #pragma unroll
        for (int ks = 0; ks < 4; ++ks) {
            const int ko = ks * 32 + lq * 8;
            bf16x8 a0 = *(const bf16x8*)&As[wave * 32 + lr][ko];
            bf16x8 a1 = *(const bf16x8*)&As[wave * 32 + 16 + lr][ko];
            #pragma unroll
            for (int nt = 0; nt < 8; ++nt) {
                bf16x8 b = *(const bf16x8*)&Bs[nt * 16 + lr][ko];
                acc[0][nt] = __builtin_amdgcn_mfma_f32_16x16x32_bf16(a0, b, acc[0][nt], 0, 0, 0);
                acc[1][nt] = __builtin_amdgcn_mfma_f32_16x16x32_bf16(a1, b, acc[1][nt], 0, 0, 0);
            }
        }
        __syncthreads();                    // all MFMA reads of Bs done

        // repack C-layout -> canonical bf16 rows in Bs
        float bv[8];
        #pragma unroll
        for (int nt = 0; nt < 8; ++nt) bv[nt] = (r == NR) ? bias1[nt * 16 + lr] : 0.f;
        #pragma unroll
        for (int mt = 0; mt < 2; ++mt)
            #pragma unroll
            for (int nt = 0; nt < 8; ++nt)
                #pragma unroll
                for (int reg = 0; reg < 4; ++reg) {
                    int ml = wave * 32 + mt * 16 + lq * 4 + reg;   // own slab only
                    Bs[ml][nt * 16 + lr] = f2bf(acc[mt][nt][reg] + bv[nt]);
                }
        __syncthreads();

        if (r < NR) {
            unsigned* dst = xw8 + ((size_t)r * Nn + rowbase) * (DH / 4);
            #pragma unroll
            for (int it = 0; it < 8; ++it) {
                int c = it * 256 + tid;
                int row = c >> 4, col = c & 15;
                if (rowbase + row < Nn) {
                    uint4 q = *(uint4*)&Bs[row][col * 8];
                    uint2 o;
                    o.x = __builtin_amdgcn_cvt_pk_fp8_f32(bflo(q.x), bfhi(q.x), 0, false);
                    o.x = __builtin_amdgcn_cvt_pk_fp8_f32(bflo(q.y), bfhi(q.y), o.x, true);
                    o.y = __builtin_amdgcn_cvt_pk_fp8_f32(bflo(q.z), bfhi(q.z), 0, false);
                    o.y = __builtin_amdgcn_cvt_pk_fp8_f32(bflo(q.w), bfhi(q.w), o.y, true);
                    *(uint2*)&dst[(size_t)row * (DH / 4) + col * 2] = o;
                }
            }
        } else {
            #pragma unroll
            for (int it = 0; it < 8; ++it) {
                int c = it * 256 + tid;
                int row = c >> 4, col = c & 15;
                if (rowbase + row < Nn)
                    *(uint4*)&hb[((size_t)(rowbase + row)) * DH + col * 8] = *(uint4*)&Bs[row][col * 8];
            }
        }
    }
}

// ---------- pass-1 aggregation: one wave per dst, fp8 gather, 2 edges/step x8 ----------
// hbf[dst] = bf16( hb[dst] + (1/deg) * sum_e xw8[type_e][src_e] )
__global__ __launch_bounds__(256) void k_agg1(const int* __restrict__ offsets,
                                              const unsigned* __restrict__ sorted,
                                              const unsigned* __restrict__ xw8,
                                              const unsigned* __restrict__ hb32,
                                              int Nn, unsigned* __restrict__ hbf) {
    int w = (blockIdx.x * blockDim.x + threadIdx.x) >> 6;
    if (w >= Nn) return;
    int lane = threadIdx.x & 63;
    int half = lane >> 5, sub = lane & 31;    // half-wave h reads edge 2j+h, 4 features/lane
    int s = offsets[w], e = offsets[w + 1];
    float a0 = 0.f, a1 = 0.f, a2 = 0.f, a3 = 0.f;
    for (int p = s; p < e; p += 16) {
        unsigned pk[8]; float m[8];
        #pragma unroll
        for (int j = 0; j < 8; ++j) {
            int q = p + 2 * j + half; bool v = q < e;
            pk[j] = sorted[v ? q : e - 1];
            m[j] = v ? 1.f : 0.f;
        }
        unsigned u[8];
        #pragma unroll
        for (int j = 0; j < 8; ++j)
            u[j] = xw8[((size_t)(pk[j] >> 17) * Nn + (pk[j] & 0x1FFFFu)) * 32 + sub];
        #pragma unroll
        for (int j = 0; j < 8; ++j) {
            f32x2 lo = __builtin_amdgcn_cvt_pk_f32_fp8(u[j], false);
            f32x2 hi = __builtin_amdgcn_cvt_pk_f32_fp8(u[j], true);
            a0 = fmaf(m[j], lo.x, a0);
            a1 = fmaf(m[j], lo.y, a1);
            a2 = fmaf(m[j], hi.x, a2);
            a3 = fmaf(m[j], hi.y, a3);
        }
    }
    a0 += __shfl_xor(a0, 32, 64);
    a1 += __shfl_xor(a1, 32, 64);
    a2 += __shfl_xor(a2, 32, 64);
    a3 += __shfl_xor(a3, 32, 64);
    if (half == 0) {
        float invd = 1.0f / fmaxf((float)(e - s), 1.0f);
        uint2 hv = *(const uint2*)&hb32[(size_t)w * 64 + sub * 2];
        float h0 = bflo(hv.x) + a0 * invd;
        float h1 = bfhi(hv.x) + a1 * invd;
        float h2 = bflo(hv.y) + a2 * invd;
        float h3 = bfhi(hv.y) + a3 * invd;
        uint2 o;
        o.x = (unsigned)f2bf(h0) | ((unsigned)f2bf(h1) << 16);
        o.y = (unsigned)f2bf(h2) | ((unsigned)f2bf(h3) << 16);
        *(uint2*)&hbf[(size_t)w * 64 + sub * 2] = o;
    }
}

// ---------- pass-2 aggregation: nbrbf[dst] = bf16( sum_e hbf[src_e] ) ----------
__global__ __launch_bounds__(256) void k_agg2(const int* __restrict__ offsets,
                                              const unsigned* __restrict__ sorted,
                                              const unsigned* __restrict__ hbf32,
                                              int Nn, unsigned* __restrict__ nbrbf) {
    int w = (blockIdx.x * blockDim.x + threadIdx.x) >> 6;
    if (w >= Nn) return;
    int lane = threadIdx.x & 63;
    int s = offsets[w], e = offsets[w + 1];
    float ax = 0.f, ay = 0.f;
    for (int p = s; p < e; p += 16) {
        unsigned pk[16]; float m[16];
        #pragma unroll
        for (int j = 0; j < 16; ++j) {
            int q = p + j; bool v = q < e;
            pk[j] = sorted[v ? q : e - 1];
            m[j] = v ? 1.f : 0.f;
        }
        unsigned u[16];
        #pragma unroll
        for (int j = 0; j < 16; ++j)
            u[j] = hbf32[(size_t)(pk[j] & 0x1FFFFu) * 64 + lane];
        #pragma unroll
        for (int j = 0; j < 16; ++j) {
            ax = fmaf(m[j], __uint_as_float(u[j] << 16), ax);
            ay = fmaf(m[j], __uint_as_float(u[j] & 0xffff0000u), ay);
        }
    }
    nbrbf[(size_t)w * 64 + lane] = (unsigned)f2bf(ax) | ((unsigned)f2bf(ay) << 16);
}

// ---------- MFMA GEMM2: out = nbr@w_rel + h@w_root2 + bias2 (K=256 in 2 phases) ----------
__global__ __launch_bounds__(256) void k_gemm2m(const unsigned short* __restrict__ nbrbf,
                                                const unsigned short* __restrict__ hbf,
                                                const unsigned short* __restrict__ WT2,
                                                const float* __restrict__ bias2,
                                                int Nn, float* __restrict__ out) {
    __shared__ __align__(16) unsigned short As[128][136];
    __shared__ __align__(16) unsigned short Bs[128][136];
    const int tid = threadIdx.x;
    const int wave = tid >> 6, lane = tid & 63;
    const int rowbase = blockIdx.x * 128;
    const int lq = lane >> 4, lr = lane & 15;

    f32x4 acc[2][8];
    #pragma unroll
    for (int mt = 0; mt < 2; ++mt)
        #pragma unroll
        for (int nt = 0; nt < 8; ++nt) acc[mt][nt] = (f32x4)0.f;

    for (int ph = 0; ph < 2; ++ph) {
        const unsigned short* A = ph ? hbf : nbrbf;
        const unsigned short* WT = WT2 + (size_t)ph * DH * DH;
        if (ph) __syncthreads();
        #pragma unroll
        for (int it = 0; it < 8; ++it) {
            int c = it * 256 + tid;
            int row = c >> 4, col = c & 15;
            int rg = rowbase + row; if (rg >= Nn) rg = Nn - 1;
            *(uint4*)&As[row][col * 8] = *(const uint4*)&A[(size_t)rg * DH + col * 8];
            *(uint4*)&Bs[row][col * 8] = *(const uint4*)&WT[(size_t)row * DH + col * 8];
        }
        __syncthreads();
        #pragma unroll
        for (int ks = 0; ks < 4; ++ks) {
            const int ko = ks * 32 + lq * 8;
            bf16x8 a0 = *(const bf16x8*)&As[wave * 32 + lr][ko];
            bf16x8 a1 = *(const bf16x8*)&As[wave * 32 + 16 + lr][ko];
            #pragma unroll
            for (int nt = 0; nt < 8; ++nt) {
                bf16x8 b = *(const bf16x8*)&Bs[nt * 16 + lr][ko];
                acc[0][nt] = __builtin_amdgcn_mfma_f32_16x16x32_bf16(a0, b, acc[0][nt], 0, 0, 0);
                acc[1][nt] = __builtin_amdgcn_mfma_f32_16x16x32_bf16(a1, b, acc[1][nt], 0, 0, 0);
            }
        }
    }

    float bv[8];
    #pragma unroll
    for (int nt = 0; nt < 8; ++nt) bv[nt] = bias2[nt * 16 + lr];
    #pragma unroll
    for (int mt = 0; mt < 2; ++mt)
        #pragma unroll
        for (int nt = 0; nt < 8; ++nt)
            #pragma unroll
            for (int reg = 0; reg < 4; ++reg) {
                int m = rowbase + wave * 32 + mt * 16 + lq * 4 + reg;
                if (m < Nn) out[(size_t)m * DH + nt * 16 + lr] = acc[mt][nt][reg] + bv[nt];
            }
}

extern "C" void kernel_launch(void* const* d_in, const int* in_sizes, int n_in,
                              void* d_out, int out_size, void* d_ws, size_t ws_size,
                              hipStream_t stream) {
    const float* x      = (const float*)d_in[0];
    const int*   eidx   = (const int*)d_in[1];
    // d_in[2] = edge_norm: unused by the reference computation
    const int*   etype  = (const int*)d_in[3];
    const float* basis  = (const float*)d_in[4];
    const float* comp   = (const float*)d_in[5];
    const float* root   = (const float*)d_in[6];
    const float* bias1  = (const float*)d_in[7];
    const float* wrel   = (const float*)d_in[8];
    const float* wroot2 = (const float*)d_in[9];
    const float* bias2  = (const float*)d_in[10];
    float* out = (float*)d_out;

    const int N = in_sizes[0] / DH;    // 40000
    const int E = in_sizes[3];         // 640000
    const int* srcA = eidx;
    const int* dstA = eidx + E;

    char* ws = (char*)d_ws;
    size_t off = 0;
    auto alloc = [&](size_t bytes) -> void* {
        void* p = (void*)(ws + off);
        off += (bytes + 255) & ~(size_t)255;
        return p;
    };
    int* deg           = (int*)alloc((size_t)N * 4);
    int* cursor        = (int*)alloc((size_t)N * 4);
    int* offsets       = (int*)alloc((size_t)(N + 1) * 4);
    int* partial       = (int*)alloc(256 * 4);
    unsigned* sorted   = (unsigned*)alloc((size_t)E * 4);
    unsigned short* wallT = (unsigned short*)alloc((size_t)(NR + 1) * DH * DH * 2);
    unsigned short* WT2   = (unsigned short*)alloc((size_t)2 * DH * DH * 2);
    unsigned* xw8      = (unsigned*)alloc((size_t)NR * N * DH);       // fp8 e4m3
    unsigned short* hb = (unsigned short*)alloc((size_t)N * DH * 2);
    unsigned* hbf      = (unsigned*)alloc((size_t)N * (DH / 2) * 4);
    unsigned* nbrbf    = (unsigned*)alloc((size_t)N * (DH / 2) * 4);
    (void)ws_size; (void)n_in; (void)out_size;

    hipMemsetAsync(deg, 0, (size_t)N * 8, stream);  // deg + cursor (contiguous)

    k_wprep<<<dim3(DH, NR + 3), DH, 0, stream>>>(comp, basis, root, wrel, wroot2, wallT, WT2);

    {   // fused CSR build (cooperative)
        void* args[] = {(void*)&srcA, (void*)&dstA, (void*)&etype, (void*)&E,
                        (void*)&deg, (void*)&offsets, (void*)&partial,
                        (void*)&cursor, (void*)&sorted, (void*)&N};
        hipLaunchCooperativeKernel((const void*)k_csr, dim3(40), dim3(1024), args, 0, stream);
    }

    const int gx = (N + 127) / 128;
    k_gemm1m<<<dim3(gx, 3), 256, 0, stream>>>(x, wallT, bias1, N, xw8, hb);
    k_agg1<<<(N * 64) / 256, 256, 0, stream>>>(offsets, sorted, xw8,
                                               (const unsigned*)hb, N, hbf);
    k_agg2<<<(N * 64) / 256, 256, 0, stream>>>(offsets, sorted, hbf, N, nbrbf);
    k_gemm2m<<<gx, 256, 0, stream>>>((const unsigned short*)nbrbf, (const unsigned short*)hbf,
                                     WT2, bias2, N, out);
}

// Round 9
// 290.160 us; speedup vs baseline: 1.1840x; 1.1840x over previous
//
#include <hip/hip_runtime.h>
#include <hip/hip_cooperative_groups.h>
#include <stdint.h>

namespace cg = cooperative_groups;

#define DH 128   // D_IN == H == 128
#define NB 30    // num bases
#define NR 8     // num relations

typedef short bf16x8 __attribute__((ext_vector_type(8)));   // 8 bf16 = 4 VGPRs
typedef float f32x4 __attribute__((ext_vector_type(4)));
typedef float f32x2 __attribute__((ext_vector_type(2)));

static __device__ __forceinline__ unsigned short f2bf(float f) {
    unsigned u = __float_as_uint(f);
    u += 0x7fffu + ((u >> 16) & 1u);   // round-to-nearest-even
    return (unsigned short)(u >> 16);
}
static __device__ __forceinline__ float bflo(unsigned u) { return __uint_as_float(u << 16); }
static __device__ __forceinline__ float bfhi(unsigned u) { return __uint_as_float(u & 0xffff0000u); }

// ---------- weight prep (transposed bf16) ----------
__global__ __launch_bounds__(128) void k_wprep(const float* __restrict__ comp,
                                               const float* __restrict__ basis,
                                               const float* __restrict__ root,
                                               const float* __restrict__ wrel,
                                               const float* __restrict__ wroot2,
                                               unsigned short* __restrict__ wallT,
                                               unsigned short* __restrict__ WT2) {
    int o = threadIdx.x;    // 0..127
    int i = blockIdx.x;     // 0..127
    int y = blockIdx.y;     // 0..10
    if (y < NR) {
        float s = 0.f;
        #pragma unroll
        for (int b = 0; b < NB; ++b)
            s += comp[y * NB + b] * basis[((size_t)b * DH + i) * DH + o];
        wallT[((size_t)y * DH + o) * DH + i] = f2bf(s);
    } else if (y == NR) {
        wallT[((size_t)NR * DH + o) * DH + i] = f2bf(root[i * DH + o]);
    } else {
        const float* W = (y == NR + 2) ? wroot2 : wrel;
        WT2[((size_t)(y - NR - 1) * DH + o) * DH + i] = f2bf(W[i * DH + o]);
    }
}

// ---------- CSR build: full-grid hist ----------
__global__ void k_hist(const int* __restrict__ dst, int E, int* __restrict__ deg) {
    int e = blockIdx.x * blockDim.x + threadIdx.x;
    if (e < E) atomicAdd(&deg[dst[e]], 1);
}

// ---------- cooperative scan over deg[0..n-1] -> exclusive offsets[0..n] (40 blocks) ----------
__global__ __launch_bounds__(1024) void k_scanC(const int* __restrict__ deg, int n,
                                                int* __restrict__ offsets,
                                                int* __restrict__ partial) {
    cg::grid_group grid = cg::this_grid();
    __shared__ int s[1024];
    __shared__ int pre_s;
    const int tid = threadIdx.x;
    const int b = blockIdx.x;
    int i = b * 1024 + tid;
    int v = (i < n) ? deg[i] : 0;
    s[tid] = v;
    __syncthreads();
    for (int off = 1; off < 1024; off <<= 1) {
        int t = (tid >= off) ? s[tid - off] : 0;
        __syncthreads();
        s[tid] += t;
        __syncthreads();
    }
    if (i <= n) offsets[i] = s[tid] - v;   // exclusive, local
    if (tid == 1023) partial[b] = s[1023];
    grid.sync();
    if (tid == 0) {
        int pre = 0;
        for (int t = 0; t < b; ++t) pre += partial[t];
        pre_s = pre;
    }
    __syncthreads();
    if (i <= n) offsets[i] += pre_s;
}

// ---------- CSR build: full-grid scatter ----------
__global__ void k_scatter(const int* __restrict__ src, const int* __restrict__ dstA,
                          const int* __restrict__ etype, int E,
                          const int* __restrict__ offsets, int* __restrict__ cursor,
                          unsigned* __restrict__ sorted) {
    int e = blockIdx.x * blockDim.x + threadIdx.x;
    if (e >= E) return;
    int d = dstA[e];
    int pos = offsets[d] + atomicAdd(&cursor[d], 1);
    sorted[pos] = (unsigned)src[e] | ((unsigned)etype[e] << 17);  // src<2^17, type<8
}

// ---------- MFMA GEMM1: 128x128 tile, K=128, grid (ceil(N/128), 3) ----------
// Stages fp32 X -> bf16 LDS directly. blockIdx.y=g handles relations r = 3g..3g+2.
// r<8: xw8[r] = fp8(X @ W_r). r==8: hb = bf16(X @ root + bias1)
__global__ __launch_bounds__(256) void k_gemm1m(const float* __restrict__ x,
                                                const unsigned short* __restrict__ wallT,
                                                const float* __restrict__ bias1,
                                                int Nn,
                                                unsigned* __restrict__ xw8,
                                                unsigned short* __restrict__ hb) {
    __shared__ __align__(16) unsigned short As[128][136];  // [m][k], +8 pad
    __shared__ __align__(16) unsigned short Bs[128][136];  // [n][k] / epilogue repack
    const int tid = threadIdx.x;
    const int wave = tid >> 6, lane = tid & 63;
    const int g = blockIdx.y;
    const int rowbase = blockIdx.x * 128;
    const int lq = lane >> 4, lr = lane & 15;

    // stage A once: fp32 -> bf16 on the fly
    #pragma unroll
    for (int it = 0; it < 8; ++it) {
        int c = it * 256 + tid;
        int row = c >> 4, col = c & 15;
        int rg = rowbase + row; if (rg >= Nn) rg = Nn - 1;
        float4 v0 = *(const float4*)&x[(size_t)rg * DH + col * 8];
        float4 v1 = *(const float4*)&x[(size_t)rg * DH + col * 8 + 4];
        uint4 u;
        u.x = (unsigned)f2bf(v0.x) | ((unsigned)f2bf(v0.y) << 16);
        u.y = (unsigned)f2bf(v0.z) | ((unsigned)f2bf(v0.w) << 16);
        u.z = (unsigned)f2bf(v1.x) | ((unsigned)f2bf(v1.y) << 16);
        u.w = (unsigned)f2bf(v1.z) | ((unsigned)f2bf(v1.w) << 16);
        *(uint4*)&As[row][col * 8] = u;
    }

    for (int rr = 0; rr < 3; ++rr) {
        const int r = g * 3 + rr;
        const unsigned short* WT = wallT + (size_t)r * DH * DH;
        if (rr) __syncthreads();            // prior epilogue reads of Bs done
        #pragma unroll
        for (int it = 0; it < 8; ++it) {
            int c = it * 256 + tid;
            int row = c >> 4, col = c & 15;
            *(uint4*)&Bs[row][col * 8] = *(const uint4*)&WT[(size_t)row * DH + col * 8];
        }
        __syncthreads();                    // also covers As on first iter

        f32x4 acc[2][8];
        #pragma unroll
        for (int mt = 0; mt < 2; ++mt)
            #pragma unroll
            for (int nt = 0; nt < 8; ++nt) acc[mt][nt] = (f32x4)0.f;

        #pragma unroll
        for (int ks = 0; ks < 4; ++ks) {
            const int ko = ks * 32 + lq * 8;
            bf16x8 a0 = *(const bf16x8*)&As[wave * 32 + lr][ko];
            bf16x8 a1 = *(const bf16x8*)&As[wave * 32 + 16 + lr][ko];
            #pragma unroll
            for (int nt = 0; nt < 8; ++nt) {
                bf16x8 b = *(const bf16x8*)&Bs[nt * 16 + lr][ko];
                acc[0][nt] = __builtin_amdgcn_mfma_f32_16x16x32_bf16(a0, b, acc[0][nt], 0, 0, 0);
                acc[1][nt] = __builtin_amdgcn_mfma_f32_16x16x32_bf16(a1, b, acc[1][nt], 0, 0, 0);
            }
        }
        __syncthreads();                    // all MFMA reads of Bs done

        // repack C-layout -> canonical bf16 rows in Bs
        float bv[8];
        #pragma unroll
        for (int nt = 0; nt < 8; ++nt) bv[nt] = (r == NR) ? bias1[nt * 16 + lr] : 0.f;
        #pragma unroll
        for (int mt = 0; mt < 2; ++mt)
            #pragma unroll
            for (int nt = 0; nt < 8; ++nt)
                #pragma unroll
                for (int reg = 0; reg < 4; ++reg) {
                    int ml = wave * 32 + mt * 16 + lq * 4 + reg;   // own slab only
                    Bs[ml][nt * 16 + lr] = f2bf(acc[mt][nt][reg] + bv[nt]);
                }
        __syncthreads();

        if (r < NR) {
            unsigned* dst = xw8 + ((size_t)r * Nn + rowbase) * (DH / 4);
            #pragma unroll
            for (int it = 0; it < 8; ++it) {
                int c = it * 256 + tid;
                int row = c >> 4, col = c & 15;
                if (rowbase + row < Nn) {
                    uint4 q = *(uint4*)&Bs[row][col * 8];
                    uint2 o;
                    o.x = __builtin_amdgcn_cvt_pk_fp8_f32(bflo(q.x), bfhi(q.x), 0, false);
                    o.x = __builtin_amdgcn_cvt_pk_fp8_f32(bflo(q.y), bfhi(q.y), o.x, true);
                    o.y = __builtin_amdgcn_cvt_pk_fp8_f32(bflo(q.z), bfhi(q.z), 0, false);
                    o.y = __builtin_amdgcn_cvt_pk_fp8_f32(bflo(q.w), bfhi(q.w), o.y, true);
                    *(uint2*)&dst[(size_t)row * (DH / 4) + col * 2] = o;
                }
            }
        } else {
            #pragma unroll
            for (int it = 0; it < 8; ++it) {
                int c = it * 256 + tid;
                int row = c >> 4, col = c & 15;
                if (rowbase + row < Nn)
                    *(uint4*)&hb[((size_t)(rowbase + row)) * DH + col * 8] = *(uint4*)&Bs[row][col * 8];
            }
        }
    }
}

// ---------- pass-1 aggregation: one wave per dst, fp8 gather, 2 edges/step x8 ----------
// hbf[dst] = bf16( hb[dst] + (1/deg) * sum_e xw8[type_e][src_e] )
__global__ __launch_bounds__(256) void k_agg1(const int* __restrict__ offsets,
                                              const unsigned* __restrict__ sorted,
                                              const unsigned* __restrict__ xw8,
                                              const unsigned* __restrict__ hb32,
                                              int Nn, unsigned* __restrict__ hbf) {
    int w = (blockIdx.x * blockDim.x + threadIdx.x) >> 6;
    if (w >= Nn) return;
    int lane = threadIdx.x & 63;
    int half = lane >> 5, sub = lane & 31;    // half-wave h reads edge 2j+h, 4 features/lane
    int s = offsets[w], e = offsets[w + 1];
    float a0 = 0.f, a1 = 0.f, a2 = 0.f, a3 = 0.f;
    for (int p = s; p < e; p += 16) {
        unsigned pk[8]; float m[8];
        #pragma unroll
        for (int j = 0; j < 8; ++j) {
            int q = p + 2 * j + half; bool v = q < e;
            pk[j] = sorted[v ? q : e - 1];
            m[j] = v ? 1.f : 0.f;
        }
        unsigned u[8];
        #pragma unroll
        for (int j = 0; j < 8; ++j)
            u[j] = xw8[((size_t)(pk[j] >> 17) * Nn + (pk[j] & 0x1FFFFu)) * 32 + sub];
        #pragma unroll
        for (int j = 0; j < 8; ++j) {
            f32x2 lo = __builtin_amdgcn_cvt_pk_f32_fp8(u[j], false);
            f32x2 hi = __builtin_amdgcn_cvt_pk_f32_fp8(u[j], true);
            a0 = fmaf(m[j], lo.x, a0);
            a1 = fmaf(m[j], lo.y, a1);
            a2 = fmaf(m[j], hi.x, a2);
            a3 = fmaf(m[j], hi.y, a3);
        }
    }
    a0 += __shfl_xor(a0, 32, 64);
    a1 += __shfl_xor(a1, 32, 64);
    a2 += __shfl_xor(a2, 32, 64);
    a3 += __shfl_xor(a3, 32, 64);
    if (half == 0) {
        float invd = 1.0f / fmaxf((float)(e - s), 1.0f);
        uint2 hv = *(const uint2*)&hb32[(size_t)w * 64 + sub * 2];
        float h0 = bflo(hv.x) + a0 * invd;
        float h1 = bfhi(hv.x) + a1 * invd;
        float h2 = bflo(hv.y) + a2 * invd;
        float h3 = bfhi(hv.y) + a3 * invd;
        uint2 o;
        o.x = (unsigned)f2bf(h0) | ((unsigned)f2bf(h1) << 16);
        o.y = (unsigned)f2bf(h2) | ((unsigned)f2bf(h3) << 16);
        *(uint2*)&hbf[(size_t)w * 64 + sub * 2] = o;
    }
}

// ---------- pass-2 aggregation: bf16 gather; nbrbf[dst] = bf16( sum_e h[src_e] ) ----------
__global__ __launch_bounds__(256) void k_agg2(const int* __restrict__ offsets,
                                              const unsigned* __restrict__ sorted,
                                              const unsigned* __restrict__ hbf32,
                                              int Nn, unsigned* __restrict__ nbrbf) {
    int w = (blockIdx.x * blockDim.x + threadIdx.x) >> 6;
    if (w >= Nn) return;
    int lane = threadIdx.x & 63;
    int s = offsets[w], e = offsets[w + 1];
    float ax = 0.f, ay = 0.f;
    for (int p = s; p < e; p += 16) {
        unsigned pk[16]; float m[16];
        #pragma unroll
        for (int j = 0; j < 16; ++j) {
            int q = p + j; bool v = q < e;
            pk[j] = sorted[v ? q : e - 1];
            m[j] = v ? 1.f : 0.f;
        }
        unsigned u[16];
        #pragma unroll
        for (int j = 0; j < 16; ++j)
            u[j] = hbf32[(size_t)(pk[j] & 0x1FFFFu) * 64 + lane];
        #pragma unroll
        for (int j = 0; j < 16; ++j) {
            ax = fmaf(m[j], __uint_as_float(u[j] << 16), ax);
            ay = fmaf(m[j], __uint_as_float(u[j] & 0xffff0000u), ay);
        }
    }
    nbrbf[(size_t)w * 64 + lane] = (unsigned)f2bf(ax) | ((unsigned)f2bf(ay) << 16);
}

// ---------- MFMA GEMM2: out = nbr@w_rel + h@w_root2 + bias2 (K=256 in 2 phases) ----------
__global__ __launch_bounds__(256) void k_gemm2m(const unsigned short* __restrict__ nbrbf,
                                                const unsigned short* __restrict__ hbf,
                                                const unsigned short* __restrict__ WT2,
                                                const float* __restrict__ bias2,
                                                int Nn, float* __restrict__ out) {
    __shared__ __align__(16) unsigned short As[128][136];
    __shared__ __align__(16) unsigned short Bs[128][136];
    const int tid = threadIdx.x;
    const int wave = tid >> 6, lane = tid & 63;
    const int rowbase = blockIdx.x * 128;
    const int lq = lane >> 4, lr = lane & 15;

    f32x4 acc[2][8];
    #pragma unroll
    for (int mt = 0; mt < 2; ++mt)
        #pragma unroll
        for (int nt = 0; nt < 8; ++nt) acc[mt][nt] = (f32x4)0.f;

    for (int ph = 0; ph < 2; ++ph) {
        const unsigned short* A = ph ? hbf : nbrbf;
        const unsigned short* WT = WT2 + (size_t)ph * DH * DH;
        if (ph) __syncthreads();
        #pragma unroll
        for (int it = 0; it < 8; ++it) {
            int c = it * 256 + tid;
            int row = c >> 4, col = c & 15;
            int rg = rowbase + row; if (rg >= Nn) rg = Nn - 1;
            *(uint4*)&As[row][col * 8] = *(const uint4*)&A[(size_t)rg * DH + col * 8];
            *(uint4*)&Bs[row][col * 8] = *(const uint4*)&WT[(size_t)row * DH + col * 8];
        }
        __syncthreads();
        #pragma unroll
        for (int ks = 0; ks < 4; ++ks) {
            const int ko = ks * 32 + lq * 8;
            bf16x8 a0 = *(const bf16x8*)&As[wave * 32 + lr][ko];
            bf16x8 a1 = *(const bf16x8*)&As[wave * 32 + 16 + lr][ko];
            #pragma unroll
            for (int nt = 0; nt < 8; ++nt) {
                bf16x8 b = *(const bf16x8*)&Bs[nt * 16 + lr][ko];
                acc[0][nt] = __builtin_amdgcn_mfma_f32_16x16x32_bf16(a0, b, acc[0][nt], 0, 0, 0);
                acc[1][nt] = __builtin_amdgcn_mfma_f32_16x16x32_bf16(a1, b, acc[1][nt], 0, 0, 0);
            }
        }
    }

    float bv[8];
    #pragma unroll
    for (int nt = 0; nt < 8; ++nt) bv[nt] = bias2[nt * 16 + lr];
    #pragma unroll
    for (int mt = 0; mt < 2; ++mt)
        #pragma unroll
        for (int nt = 0; nt < 8; ++nt)
            #pragma unroll
            for (int reg = 0; reg < 4; ++reg) {
                int m = rowbase + wave * 32 + mt * 16 + lq * 4 + reg;
                if (m < Nn) out[(size_t)m * DH + nt * 16 + lr] = acc[mt][nt][reg] + bv[nt];
            }
}

extern "C" void kernel_launch(void* const* d_in, const int* in_sizes, int n_in,
                              void* d_out, int out_size, void* d_ws, size_t ws_size,
                              hipStream_t stream) {
    const float* x      = (const float*)d_in[0];
    const int*   eidx   = (const int*)d_in[1];
    // d_in[2] = edge_norm: unused by the reference computation
    const int*   etype  = (const int*)d_in[3];
    const float* basis  = (const float*)d_in[4];
    const float* comp   = (const float*)d_in[5];
    const float* root   = (const float*)d_in[6];
    const float* bias1  = (const float*)d_in[7];
    const float* wrel   = (const float*)d_in[8];
    const float* wroot2 = (const float*)d_in[9];
    const float* bias2  = (const float*)d_in[10];
    float* out = (float*)d_out;

    const int N = in_sizes[0] / DH;    // 40000
    const int E = in_sizes[3];         // 640000
    const int* srcA = eidx;
    const int* dstA = eidx + E;

    char* ws = (char*)d_ws;
    size_t off = 0;
    auto alloc = [&](size_t bytes) -> void* {
        void* p = (void*)(ws + off);
        off += (bytes + 255) & ~(size_t)255;
        return p;
    };
    int* deg           = (int*)alloc((size_t)N * 4);
    int* cursor        = (int*)alloc((size_t)N * 4);
    int* offsets       = (int*)alloc((size_t)(N + 1) * 4);
    int* partial       = (int*)alloc(256 * 4);
    unsigned* sorted   = (unsigned*)alloc((size_t)E * 4);
    unsigned short* wallT = (unsigned short*)alloc((size_t)(NR + 1) * DH * DH * 2);
    unsigned short* WT2   = (unsigned short*)alloc((size_t)2 * DH * DH * 2);
    unsigned* xw8      = (unsigned*)alloc((size_t)NR * N * DH);       // fp8 e4m3
    unsigned short* hb = (unsigned short*)alloc((size_t)N * DH * 2);
    unsigned* hbf      = (unsigned*)alloc((size_t)N * (DH / 2) * 4);
    unsigned* nbrbf    = (unsigned*)alloc((size_t)N * (DH / 2) * 4);
    (void)ws_size; (void)n_in; (void)out_size;

    hipMemsetAsync(deg, 0, (size_t)N * 8, stream);  // deg + cursor (contiguous)

    k_wprep<<<dim3(DH, NR + 3), DH, 0, stream>>>(comp, basis, root, wrel, wroot2, wallT, WT2);
    k_hist<<<(E + 255) / 256, 256, 0, stream>>>(dstA, E, deg);
    {   // cooperative scan (40 blocks: scan of 40001 ints)
        void* args[] = {(void*)&deg, (void*)&N, (void*)&offsets, (void*)&partial};
        hipLaunchCooperativeKernel((const void*)k_scanC, dim3(40), dim3(1024), args, 0, stream);
    }
    k_scatter<<<(E + 255) / 256, 256, 0, stream>>>(srcA, dstA, etype, E, offsets, cursor, sorted);

    const int gx = (N + 127) / 128;
    k_gemm1m<<<dim3(gx, 3), 256, 0, stream>>>(x, wallT, bias1, N, xw8, hb);
    k_agg1<<<(N * 64) / 256, 256, 0, stream>>>(offsets, sorted, xw8,
                                               (const unsigned*)hb, N, hbf);
    k_agg2<<<(N * 64) / 256, 256, 0, stream>>>(offsets, sorted, hbf, N, nbrbf);
    k_gemm2m<<<gx, 256, 0, stream>>>((const unsigned short*)nbrbf, (const unsigned short*)hbf,
                                     WT2, bias2, N, out);
}

// Round 10
// 245.171 us; speedup vs baseline: 1.4013x; 1.1835x over previous
//
#include <hip/hip_runtime.h>
#include <stdint.h>

#define DH 128   // D_IN == H == 128
#define NB 30    // num bases
#define NR 8     // num relations

typedef short bf16x8 __attribute__((ext_vector_type(8)));   // 8 bf16 = 4 VGPRs
typedef float f32x4 __attribute__((ext_vector_type(4)));
typedef float f32x2 __attribute__((ext_vector_type(2)));

static __device__ __forceinline__ unsigned short f2bf(float f) {
    unsigned u = __float_as_uint(f);
    u += 0x7fffu + ((u >> 16) & 1u);   // round-to-nearest-even
    return (unsigned short)(u >> 16);
}
static __device__ __forceinline__ float bflo(unsigned u) { return __uint_as_float(u << 16); }
static __device__ __forceinline__ float bfhi(unsigned u) { return __uint_as_float(u & 0xffff0000u); }

// ---------- merged weight-prep + edge histogram ----------
// blocks [0, histB): histogram of dst.  blocks [histB, histB+704): wprep units.
__global__ __launch_bounds__(256) void k_prephist(const float* __restrict__ comp,
                                                  const float* __restrict__ basis,
                                                  const float* __restrict__ root,
                                                  const float* __restrict__ wrel,
                                                  const float* __restrict__ wroot2,
                                                  unsigned short* __restrict__ wallT,
                                                  unsigned short* __restrict__ WT2,
                                                  const int* __restrict__ dstA, int E,
                                                  int* __restrict__ deg, int histB) {
    int b = blockIdx.x;
    int tid = threadIdx.x;
    if (b < histB) {
        int e = b * 256 + tid;
        if (e < E) atomicAdd(&deg[dstA[e]], 1);
        return;
    }
    int unit = (b - histB) * 2 + (tid >> 7);   // 0..1407 = y*128 + i
    int o = tid & 127;
    int i = unit & 127;
    int y = unit >> 7;                          // 0..10
    if (y < NR) {
        float s = 0.f;
        #pragma unroll
        for (int bb = 0; bb < NB; ++bb)
            s += comp[y * NB + bb] * basis[((size_t)bb * DH + i) * DH + o];
        wallT[((size_t)y * DH + o) * DH + i] = f2bf(s);
    } else if (y == NR) {
        wallT[((size_t)NR * DH + o) * DH + i] = f2bf(root[i * DH + o]);
    } else {
        const float* W = (y == NR + 2) ? wroot2 : wrel;
        WT2[((size_t)(y - NR - 1) * DH + o) * DH + i] = f2bf(W[i * DH + o]);
    }
}

// ---------- scan stage 1: per-block inclusive scan -> local-exclusive offsets + block totals ----------
__global__ __launch_bounds__(1024) void k_scan1(const int* __restrict__ deg, int n, int total_n,
                                                int* __restrict__ offsets, int* __restrict__ partial) {
    __shared__ int s[1024];
    int tid = threadIdx.x;
    int i = blockIdx.x * 1024 + tid;
    int v = (i < n) ? deg[i] : 0;
    s[tid] = v;
    __syncthreads();
    for (int off = 1; off < 1024; off <<= 1) {
        int t = (tid >= off) ? s[tid - off] : 0;
        __syncthreads();
        s[tid] += t;
        __syncthreads();
    }
    if (i < total_n) offsets[i] = s[tid] - v;   // exclusive, local
    if (tid == 1023) partial[blockIdx.x] = s[1023];
}

// ---------- scan stage 2+3 merged: each block adds prefix of partials (<=40 adds by t0) ----------
__global__ __launch_bounds__(1024) void k_scan3(int* __restrict__ offsets,
                                                const int* __restrict__ partial, int total_n) {
    __shared__ int pre_s;
    if (threadIdx.x == 0) {
        int pre = 0;
        for (int t = 0; t < (int)blockIdx.x; ++t) pre += partial[t];
        pre_s = pre;
    }
    __syncthreads();
    int i = blockIdx.x * 1024 + threadIdx.x;
    if (i < total_n) offsets[i] += pre_s;
}

// ---------- CSR build: full-grid scatter ----------
__global__ void k_scatter(const int* __restrict__ src, const int* __restrict__ dstA,
                          const int* __restrict__ etype, int E,
                          const int* __restrict__ offsets, int* __restrict__ cursor,
                          unsigned* __restrict__ sorted) {
    int e = blockIdx.x * blockDim.x + threadIdx.x;
    if (e >= E) return;
    int d = dstA[e];
    int pos = offsets[d] + atomicAdd(&cursor[d], 1);
    sorted[pos] = (unsigned)src[e] | ((unsigned)etype[e] << 17);  // src<2^17, type<8
}

// ---------- MFMA GEMM1: 128x128 tile, K=128, grid (ceil(N/128), 3) ----------
// Stages fp32 X -> bf16 LDS directly. blockIdx.y=g handles relations r = 3g..3g+2.
// r<8: xw8[r] = fp8(X @ W_r). r==8: hb = bf16(X @ root + bias1)
__global__ __launch_bounds__(256) void k_gemm1m(const float* __restrict__ x,
                                                const unsigned short* __restrict__ wallT,
                                                const float* __restrict__ bias1,
                                                int Nn,
                                                unsigned* __restrict__ xw8,
                                                unsigned short* __restrict__ hb) {
    __shared__ __align__(16) unsigned short As[128][136];  // [m][k], +8 pad
    __shared__ __align__(16) unsigned short Bs[128][136];  // [n][k] / epilogue repack
    const int tid = threadIdx.x;
    const int wave = tid >> 6, lane = tid & 63;
    const int g = blockIdx.y;
    const int rowbase = blockIdx.x * 128;
    const int lq = lane >> 4, lr = lane & 15;

    // stage A once: fp32 -> bf16 on the fly
    #pragma unroll
    for (int it = 0; it < 8; ++it) {
        int c = it * 256 + tid;
        int row = c >> 4, col = c & 15;
        int rg = rowbase + row; if (rg >= Nn) rg = Nn - 1;
        float4 v0 = *(const float4*)&x[(size_t)rg * DH + col * 8];
        float4 v1 = *(const float4*)&x[(size_t)rg * DH + col * 8 + 4];
        uint4 u;
        u.x = (unsigned)f2bf(v0.x) | ((unsigned)f2bf(v0.y) << 16);
        u.y = (unsigned)f2bf(v0.z) | ((unsigned)f2bf(v0.w) << 16);
        u.z = (unsigned)f2bf(v1.x) | ((unsigned)f2bf(v1.y) << 16);
        u.w = (unsigned)f2bf(v1.z) | ((unsigned)f2bf(v1.w) << 16);
        *(uint4*)&As[row][col * 8] = u;
    }

    for (int rr = 0; rr < 3; ++rr) {
        const int r = g * 3 + rr;
        const unsigned short* WT = wallT + (size_t)r * DH * DH;
        if (rr) __syncthreads();            // prior epilogue reads of Bs done
        #pragma unroll
        for (int it = 0; it < 8; ++it) {
            int c = it * 256 + tid;
            int row = c >> 4, col = c & 15;
            *(uint4*)&Bs[row][col * 8] = *(const uint4*)&WT[(size_t)row * DH + col * 8];
        }
        __syncthreads();                    // also covers As on first iter

        f32x4 acc[2][8];
        #pragma unroll
        for (int mt = 0; mt < 2; ++mt)
            #pragma unroll
            for (int nt = 0; nt < 8; ++nt) acc[mt][nt] = (f32x4)0.f;

        #pragma unroll
        for (int ks = 0; ks < 4; ++ks) {
            const int ko = ks * 32 + lq * 8;
            bf16x8 a0 = *(const bf16x8*)&As[wave * 32 + lr][ko];
            bf16x8 a1 = *(const bf16x8*)&As[wave * 32 + 16 + lr][ko];
            #pragma unroll
            for (int nt = 0; nt < 8; ++nt) {
                bf16x8 b = *(const bf16x8*)&Bs[nt * 16 + lr][ko];
                acc[0][nt] = __builtin_amdgcn_mfma_f32_16x16x32_bf16(a0, b, acc[0][nt], 0, 0, 0);
                acc[1][nt] = __builtin_amdgcn_mfma_f32_16x16x32_bf16(a1, b, acc[1][nt], 0, 0, 0);
            }
        }
        __syncthreads();                    // all MFMA reads of Bs done

        // repack C-layout -> canonical bf16 rows in Bs
        float bv[8];
        #pragma unroll
        for (int nt = 0; nt < 8; ++nt) bv[nt] = (r == NR) ? bias1[nt * 16 + lr] : 0.f;
        #pragma unroll
        for (int mt = 0; mt < 2; ++mt)
            #pragma unroll
            for (int nt = 0; nt < 8; ++nt)
                #pragma unroll
                for (int reg = 0; reg < 4; ++reg) {
                    int ml = wave * 32 + mt * 16 + lq * 4 + reg;   // own slab only
                    Bs[ml][nt * 16 + lr] = f2bf(acc[mt][nt][reg] + bv[nt]);
                }
        __syncthreads();

        if (r < NR) {
            unsigned* dst = xw8 + ((size_t)r * Nn + rowbase) * (DH / 4);
            #pragma unroll
            for (int it = 0; it < 8; ++it) {
                int c = it * 256 + tid;
                int row = c >> 4, col = c & 15;
                if (rowbase + row < Nn) {
                    uint4 q = *(uint4*)&Bs[row][col * 8];
                    uint2 o;
                    o.x = __builtin_amdgcn_cvt_pk_fp8_f32(bflo(q.x), bfhi(q.x), 0, false);
                    o.x = __builtin_amdgcn_cvt_pk_fp8_f32(bflo(q.y), bfhi(q.y), o.x, true);
                    o.y = __builtin_amdgcn_cvt_pk_fp8_f32(bflo(q.z), bfhi(q.z), 0, false);
                    o.y = __builtin_amdgcn_cvt_pk_fp8_f32(bflo(q.w), bfhi(q.w), o.y, true);
                    *(uint2*)&dst[(size_t)row * (DH / 4) + col * 2] = o;
                }
            }
        } else {
            #pragma unroll
            for (int it = 0; it < 8; ++it) {
                int c = it * 256 + tid;
                int row = c >> 4, col = c & 15;
                if (rowbase + row < Nn)
                    *(uint4*)&hb[((size_t)(rowbase + row)) * DH + col * 8] = *(uint4*)&Bs[row][col * 8];
            }
        }
    }
}

// ---------- pass-1 aggregation: one wave per dst, fp8 gather, 2 edges/step x8 ----------
// hbf[dst] = bf16( hb[dst] + (1/deg) * sum_e xw8[type_e][src_e] )
__global__ __launch_bounds__(256) void k_agg1(const int* __restrict__ offsets,
                                              const unsigned* __restrict__ sorted,
                                              const unsigned* __restrict__ xw8,
                                              const unsigned* __restrict__ hb32,
                                              int Nn, unsigned* __restrict__ hbf) {
    int w = (blockIdx.x * blockDim.x + threadIdx.x) >> 6;
    if (w >= Nn) return;
    int lane = threadIdx.x & 63;
    int half = lane >> 5, sub = lane & 31;    // half-wave h reads edge 2j+h, 4 features/lane
    int s = offsets[w], e = offsets[w + 1];
    float a0 = 0.f, a1 = 0.f, a2 = 0.f, a3 = 0.f;
    for (int p = s; p < e; p += 16) {
        unsigned pk[8]; float m[8];
        #pragma unroll
        for (int j = 0; j < 8; ++j) {
            int q = p + 2 * j + half; bool v = q < e;
            pk[j] = sorted[v ? q : e - 1];
            m[j] = v ? 1.f : 0.f;
        }
        unsigned u[8];
        #pragma unroll
        for (int j = 0; j < 8; ++j)
            u[j] = xw8[((size_t)(pk[j] >> 17) * Nn + (pk[j] & 0x1FFFFu)) * 32 + sub];
        #pragma unroll
        for (int j = 0; j < 8; ++j) {
            f32x2 lo = __builtin_amdgcn_cvt_pk_f32_fp8(u[j], false);
            f32x2 hi = __builtin_amdgcn_cvt_pk_f32_fp8(u[j], true);
            a0 = fmaf(m[j], lo.x, a0);
            a1 = fmaf(m[j], lo.y, a1);
            a2 = fmaf(m[j], hi.x, a2);
            a3 = fmaf(m[j], hi.y, a3);
        }
    }
    a0 += __shfl_xor(a0, 32, 64);
    a1 += __shfl_xor(a1, 32, 64);
    a2 += __shfl_xor(a2, 32, 64);
    a3 += __shfl_xor(a3, 32, 64);
    if (half == 0) {
        float invd = 1.0f / fmaxf((float)(e - s), 1.0f);
        uint2 hv = *(const uint2*)&hb32[(size_t)w * 64 + sub * 2];
        float h0 = bflo(hv.x) + a0 * invd;
        float h1 = bfhi(hv.x) + a1 * invd;
        float h2 = bflo(hv.y) + a2 * invd;
        float h3 = bfhi(hv.y) + a3 * invd;
        uint2 o;
        o.x = (unsigned)f2bf(h0) | ((unsigned)f2bf(h1) << 16);
        o.y = (unsigned)f2bf(h2) | ((unsigned)f2bf(h3) << 16);
        *(uint2*)&hbf[(size_t)w * 64 + sub * 2] = o;
    }
}

// ---------- pass-2 aggregation: bf16 gather; nbrbf[dst] = bf16( sum_e h[src_e] ) ----------
__global__ __launch_bounds__(256) void k_agg2(const int* __restrict__ offsets,
                                              const unsigned* __restrict__ sorted,
                                              const unsigned* __restrict__ hbf32,
                                              int Nn, unsigned* __restrict__ nbrbf) {
    int w = (blockIdx.x * blockDim.x + threadIdx.x) >> 6;
    if (w >= Nn) return;
    int lane = threadIdx.x & 63;
    int s = offsets[w], e = offsets[w + 1];
    float ax = 0.f, ay = 0.f;
    for (int p = s; p < e; p += 16) {
        unsigned pk[16]; float m[16];
        #pragma unroll
        for (int j = 0; j < 16; ++j) {
            int q = p + j; bool v = q < e;
            pk[j] = sorted[v ? q : e - 1];
            m[j] = v ? 1.f : 0.f;
        }
        unsigned u[16];
        #pragma unroll
        for (int j = 0; j < 16; ++j)
            u[j] = hbf32[(size_t)(pk[j] & 0x1FFFFu) * 64 + lane];
        #pragma unroll
        for (int j = 0; j < 16; ++j) {
            ax = fmaf(m[j], __uint_as_float(u[j] << 16), ax);
            ay = fmaf(m[j], __uint_as_float(u[j] & 0xffff0000u), ay);
        }
    }
    nbrbf[(size_t)w * 64 + lane] = (unsigned)f2bf(ax) | ((unsigned)f2bf(ay) << 16);
}

// ---------- MFMA GEMM2: out = nbr@w_rel + h@w_root2 + bias2 (K=256 in 2 phases) ----------
__global__ __launch_bounds__(256) void k_gemm2m(const unsigned short* __restrict__ nbrbf,
                                                const unsigned short* __restrict__ hbf,
                                                const unsigned short* __restrict__ WT2,
                                                const float* __restrict__ bias2,
                                                int Nn, float* __restrict__ out) {
    __shared__ __align__(16) unsigned short As[128][136];
    __shared__ __align__(16) unsigned short Bs[128][136];
    const int tid = threadIdx.x;
    const int wave = tid >> 6, lane = tid & 63;
    const int rowbase = blockIdx.x * 128;
    const int lq = lane >> 4, lr = lane & 15;

    f32x4 acc[2][8];
    #pragma unroll
    for (int mt = 0; mt < 2; ++mt)
        #pragma unroll
        for (int nt = 0; nt < 8; ++nt) acc[mt][nt] = (f32x4)0.f;

    for (int ph = 0; ph < 2; ++ph) {
        const unsigned short* A = ph ? hbf : nbrbf;
        const unsigned short* WT = WT2 + (size_t)ph * DH * DH;
        if (ph) __syncthreads();
        #pragma unroll
        for (int it = 0; it < 8; ++it) {
            int c = it * 256 + tid;
            int row = c >> 4, col = c & 15;
            int rg = rowbase + row; if (rg >= Nn) rg = Nn - 1;
            *(uint4*)&As[row][col * 8] = *(const uint4*)&A[(size_t)rg * DH + col * 8];
            *(uint4*)&Bs[row][col * 8] = *(const uint4*)&WT[(size_t)row * DH + col * 8];
        }
        __syncthreads();
        #pragma unroll
        for (int ks = 0; ks < 4; ++ks) {
            const int ko = ks * 32 + lq * 8;
            bf16x8 a0 = *(const bf16x8*)&As[wave * 32 + lr][ko];
            bf16x8 a1 = *(const bf16x8*)&As[wave * 32 + 16 + lr][ko];
            #pragma unroll
            for (int nt = 0; nt < 8; ++nt) {
                bf16x8 b = *(const bf16x8*)&Bs[nt * 16 + lr][ko];
                acc[0][nt] = __builtin_amdgcn_mfma_f32_16x16x32_bf16(a0, b, acc[0][nt], 0, 0, 0);
                acc[1][nt] = __builtin_amdgcn_mfma_f32_16x16x32_bf16(a1, b, acc[1][nt], 0, 0, 0);
            }
        }
    }

    float bv[8];
    #pragma unroll
    for (int nt = 0; nt < 8; ++nt) bv[nt] = bias2[nt * 16 + lr];
    #pragma unroll
    for (int mt = 0; mt < 2; ++mt)
        #pragma unroll
        for (int nt = 0; nt < 8; ++nt)
            #pragma unroll
            for (int reg = 0; reg < 4; ++reg) {
                int m = rowbase + wave * 32 + mt * 16 + lq * 4 + reg;
                if (m < Nn) out[(size_t)m * DH + nt * 16 + lr] = acc[mt][nt][reg] + bv[nt];
            }
}

extern "C" void kernel_launch(void* const* d_in, const int* in_sizes, int n_in,
                              void* d_out, int out_size, void* d_ws, size_t ws_size,
                              hipStream_t stream) {
    const float* x      = (const float*)d_in[0];
    const int*   eidx   = (const int*)d_in[1];
    // d_in[2] = edge_norm: unused by the reference computation
    const int*   etype  = (const int*)d_in[3];
    const float* basis  = (const float*)d_in[4];
    const float* comp   = (const float*)d_in[5];
    const float* root   = (const float*)d_in[6];
    const float* bias1  = (const float*)d_in[7];
    const float* wrel   = (const float*)d_in[8];
    const float* wroot2 = (const float*)d_in[9];
    const float* bias2  = (const float*)d_in[10];
    float* out = (float*)d_out;

    const int N = in_sizes[0] / DH;    // 40000
    const int E = in_sizes[3];         // 640000
    const int* srcA = eidx;
    const int* dstA = eidx + E;

    char* ws = (char*)d_ws;
    size_t off = 0;
    auto alloc = [&](size_t bytes) -> void* {
        void* p = (void*)(ws + off);
        off += (bytes + 255) & ~(size_t)255;
        return p;
    };
    int* deg           = (int*)alloc((size_t)N * 4);
    int* cursor        = (int*)alloc((size_t)N * 4);
    int* offsets       = (int*)alloc((size_t)(N + 1) * 4);
    int* partial       = (int*)alloc(256 * 4);
    unsigned* sorted   = (unsigned*)alloc((size_t)E * 4);
    unsigned short* wallT = (unsigned short*)alloc((size_t)(NR + 1) * DH * DH * 2);
    unsigned short* WT2   = (unsigned short*)alloc((size_t)2 * DH * DH * 2);
    unsigned* xw8      = (unsigned*)alloc((size_t)NR * N * DH);       // fp8 e4m3
    unsigned short* hb = (unsigned short*)alloc((size_t)N * DH * 2);
    unsigned* hbf      = (unsigned*)alloc((size_t)N * (DH / 2) * 4);
    unsigned* nbrbf    = (unsigned*)alloc((size_t)N * (DH / 2) * 4);
    (void)ws_size; (void)n_in; (void)out_size;

    hipMemsetAsync(deg, 0, (size_t)N * 8, stream);  // deg + cursor (contiguous)

    const int histB = (E + 255) / 256;              // 2500
    k_prephist<<<histB + 704, 256, 0, stream>>>(comp, basis, root, wrel, wroot2,
                                                wallT, WT2, dstA, E, deg, histB);

    const int totn = N + 1;
    const int nsb = (totn + 1023) / 1024;           // 40
    k_scan1<<<nsb, 1024, 0, stream>>>(deg, N, totn, offsets, partial);
    k_scan3<<<nsb, 1024, 0, stream>>>(offsets, partial, totn);
    k_scatter<<<(E + 255) / 256, 256, 0, stream>>>(srcA, dstA, etype, E, offsets, cursor, sorted);

    const int gx = (N + 127) / 128;
    k_gemm1m<<<dim3(gx, 3), 256, 0, stream>>>(x, wallT, bias1, N, xw8, hb);
    k_agg1<<<(N * 64) / 256, 256, 0, stream>>>(offsets, sorted, xw8,
                                               (const unsigned*)hb, N, hbf);
    k_agg2<<<(N * 64) / 256, 256, 0, stream>>>(offsets, sorted, hbf, N, nbrbf);
    k_gemm2m<<<gx, 256, 0, stream>>>((const unsigned short*)nbrbf, (const unsigned short*)hbf,
                                     WT2, bias2, N, out);
}

// Round 11
// 243.170 us; speedup vs baseline: 1.4128x; 1.0082x over previous
//
#include <hip/hip_runtime.h>
#include <stdint.h>

#define DH 128   // D_IN == H == 128
#define NB 30    // num bases
#define NR 8     // num relations

typedef short bf16x8 __attribute__((ext_vector_type(8)));   // 8 bf16 = 4 VGPRs
typedef float f32x4 __attribute__((ext_vector_type(4)));
typedef float f32x2 __attribute__((ext_vector_type(2)));

static __device__ __forceinline__ unsigned short f2bf(float f) {
    unsigned u = __float_as_uint(f);
    u += 0x7fffu + ((u >> 16) & 1u);   // round-to-nearest-even
    return (unsigned short)(u >> 16);
}
static __device__ __forceinline__ float bflo(unsigned u) { return __uint_as_float(u << 16); }
static __device__ __forceinline__ float bfhi(unsigned u) { return __uint_as_float(u & 0xffff0000u); }

// ---------- merged weight-prep + edge histogram ----------
// blocks [0, histB): histogram of dst.  blocks [histB, histB+704): wprep units.
__global__ __launch_bounds__(256) void k_prephist(const float* __restrict__ comp,
                                                  const float* __restrict__ basis,
                                                  const float* __restrict__ root,
                                                  const float* __restrict__ wrel,
                                                  const float* __restrict__ wroot2,
                                                  unsigned short* __restrict__ wallT,
                                                  unsigned short* __restrict__ WT2,
                                                  const int* __restrict__ dstA, int E,
                                                  int* __restrict__ deg, int histB) {
    int b = blockIdx.x;
    int tid = threadIdx.x;
    if (b < histB) {
        int e = b * 256 + tid;
        if (e < E) atomicAdd(&deg[dstA[e]], 1);
        return;
    }
    int unit = (b - histB) * 2 + (tid >> 7);   // 0..1407 = y*128 + i
    int o = tid & 127;
    int i = unit & 127;
    int y = unit >> 7;                          // 0..10
    if (y < NR) {
        float s = 0.f;
        #pragma unroll
        for (int bb = 0; bb < NB; ++bb)
            s += comp[y * NB + bb] * basis[((size_t)bb * DH + i) * DH + o];
        wallT[((size_t)y * DH + o) * DH + i] = f2bf(s);
    } else if (y == NR) {
        wallT[((size_t)NR * DH + o) * DH + i] = f2bf(root[i * DH + o]);
    } else {
        const float* W = (y == NR + 2) ? wroot2 : wrel;
        WT2[((size_t)(y - NR - 1) * DH + o) * DH + i] = f2bf(W[i * DH + o]);
    }
}

// ---------- single-pass scan: ticket-ordered decoupled lookback ----------
// st[] and ticket must be pre-zeroed. st word: flag(2b)<<62 | value. 1=aggregate, 2=prefix.
__global__ __launch_bounds__(1024) void k_scan(const int* __restrict__ deg, int n, int total_n,
                                               int* __restrict__ offsets,
                                               unsigned long long* __restrict__ st,
                                               int* __restrict__ ticket) {
    __shared__ int s[1024];
    __shared__ int bid_s, pre_s;
    const int tid = threadIdx.x;
    if (tid == 0) bid_s = atomicAdd(ticket, 1);
    __syncthreads();
    const int b = bid_s;
    int i = b * 1024 + tid;
    int v = (i < n) ? deg[i] : 0;
    s[tid] = v;
    __syncthreads();
    for (int off = 1; off < 1024; off <<= 1) {
        int t = (tid >= off) ? s[tid - off] : 0;
        __syncthreads();
        s[tid] += t;
        __syncthreads();
    }
    if (tid == 0) {
        int total = s[1023];
        atomicExch(&st[b], (1ULL << 62) | (unsigned long long)(unsigned)total);
        long long pre = 0;
        int t = b - 1;
        while (t >= 0) {
            unsigned long long w;
            do { w = atomicAdd(&st[t], 0ULL); } while (w == 0ULL);
            pre += (long long)(w & 0x3FFFFFFFFFFFFFFFULL);
            if ((w >> 62) == 2ULL) break;
            --t;
        }
        atomicExch(&st[b], (2ULL << 62) | (unsigned long long)(pre + total));
        pre_s = (int)pre;
    }
    __syncthreads();
    if (i < total_n) offsets[i] = pre_s + s[tid] - v;   // exclusive
}

// ---------- CSR build: full-grid scatter ----------
__global__ void k_scatter(const int* __restrict__ src, const int* __restrict__ dstA,
                          const int* __restrict__ etype, int E,
                          const int* __restrict__ offsets, int* __restrict__ cursor,
                          unsigned* __restrict__ sorted) {
    int e = blockIdx.x * blockDim.x + threadIdx.x;
    if (e >= E) return;
    int d = dstA[e];
    int pos = offsets[d] + atomicAdd(&cursor[d], 1);
    sorted[pos] = (unsigned)src[e] | ((unsigned)etype[e] << 17);  // src<2^17, type<8
}

// ---------- MFMA GEMM1: 128x128 tile, K=128, grid (ceil(N/128), 3) ----------
// Stages fp32 X -> bf16 LDS directly. blockIdx.y=g handles relations r = 3g..3g+2.
// r<8: xw8[r] = fp8(X @ W_r). r==8: hb = bf16(X @ root + bias1)
__global__ __launch_bounds__(256) void k_gemm1m(const float* __restrict__ x,
                                                const unsigned short* __restrict__ wallT,
                                                const float* __restrict__ bias1,
                                                int Nn,
                                                unsigned* __restrict__ xw8,
                                                unsigned short* __restrict__ hb) {
    __shared__ __align__(16) unsigned short As[128][136];  // [m][k], +8 pad
    __shared__ __align__(16) unsigned short Bs[128][136];  // [n][k] / epilogue repack
    const int tid = threadIdx.x;
    const int wave = tid >> 6, lane = tid & 63;
    const int g = blockIdx.y;
    const int rowbase = blockIdx.x * 128;
    const int lq = lane >> 4, lr = lane & 15;

    // stage A once: fp32 -> bf16 on the fly
    #pragma unroll
    for (int it = 0; it < 8; ++it) {
        int c = it * 256 + tid;
        int row = c >> 4, col = c & 15;
        int rg = rowbase + row; if (rg >= Nn) rg = Nn - 1;
        float4 v0 = *(const float4*)&x[(size_t)rg * DH + col * 8];
        float4 v1 = *(const float4*)&x[(size_t)rg * DH + col * 8 + 4];
        uint4 u;
        u.x = (unsigned)f2bf(v0.x) | ((unsigned)f2bf(v0.y) << 16);
        u.y = (unsigned)f2bf(v0.z) | ((unsigned)f2bf(v0.w) << 16);
        u.z = (unsigned)f2bf(v1.x) | ((unsigned)f2bf(v1.y) << 16);
        u.w = (unsigned)f2bf(v1.z) | ((unsigned)f2bf(v1.w) << 16);
        *(uint4*)&As[row][col * 8] = u;
    }

    for (int rr = 0; rr < 3; ++rr) {
        const int r = g * 3 + rr;
        const unsigned short* WT = wallT + (size_t)r * DH * DH;
        if (rr) __syncthreads();            // prior epilogue reads of Bs done
        #pragma unroll
        for (int it = 0; it < 8; ++it) {
            int c = it * 256 + tid;
            int row = c >> 4, col = c & 15;
            *(uint4*)&Bs[row][col * 8] = *(const uint4*)&WT[(size_t)row * DH + col * 8];
        }
        __syncthreads();                    // also covers As on first iter

        f32x4 acc[2][8];
        #pragma unroll
        for (int mt = 0; mt < 2; ++mt)
            #pragma unroll
            for (int nt = 0; nt < 8; ++nt) acc[mt][nt] = (f32x4)0.f;

        #pragma unroll
        for (int ks = 0; ks < 4; ++ks) {
            const int ko = ks * 32 + lq * 8;
            bf16x8 a0 = *(const bf16x8*)&As[wave * 32 + lr][ko];
            bf16x8 a1 = *(const bf16x8*)&As[wave * 32 + 16 + lr][ko];
            #pragma unroll
            for (int nt = 0; nt < 8; ++nt) {
                bf16x8 b = *(const bf16x8*)&Bs[nt * 16 + lr][ko];
                acc[0][nt] = __builtin_amdgcn_mfma_f32_16x16x32_bf16(a0, b, acc[0][nt], 0, 0, 0);
                acc[1][nt] = __builtin_amdgcn_mfma_f32_16x16x32_bf16(a1, b, acc[1][nt], 0, 0, 0);
            }
        }
        __syncthreads();                    // all MFMA reads of Bs done

        // repack C-layout -> canonical bf16 rows in Bs
        float bv[8];
        #pragma unroll
        for (int nt = 0; nt < 8; ++nt) bv[nt] = (r == NR) ? bias1[nt * 16 + lr] : 0.f;
        #pragma unroll
        for (int mt = 0; mt < 2; ++mt)
            #pragma unroll
            for (int nt = 0; nt < 8; ++nt)
                #pragma unroll
                for (int reg = 0; reg < 4; ++reg) {
                    int ml = wave * 32 + mt * 16 + lq * 4 + reg;   // own slab only
                    Bs[ml][nt * 16 + lr] = f2bf(acc[mt][nt][reg] + bv[nt]);
                }
        __syncthreads();

        if (r < NR) {
            unsigned* dst = xw8 + ((size_t)r * Nn + rowbase) * (DH / 4);
            #pragma unroll
            for (int it = 0; it < 8; ++it) {
                int c = it * 256 + tid;
                int row = c >> 4, col = c & 15;
                if (rowbase + row < Nn) {
                    uint4 q = *(uint4*)&Bs[row][col * 8];
                    uint2 o;
                    o.x = __builtin_amdgcn_cvt_pk_fp8_f32(bflo(q.x), bfhi(q.x), 0, false);
                    o.x = __builtin_amdgcn_cvt_pk_fp8_f32(bflo(q.y), bfhi(q.y), o.x, true);
                    o.y = __builtin_amdgcn_cvt_pk_fp8_f32(bflo(q.z), bfhi(q.z), 0, false);
                    o.y = __builtin_amdgcn_cvt_pk_fp8_f32(bflo(q.w), bfhi(q.w), o.y, true);
                    *(uint2*)&dst[(size_t)row * (DH / 4) + col * 2] = o;
                }
            }
        } else {
            #pragma unroll
            for (int it = 0; it < 8; ++it) {
                int c = it * 256 + tid;
                int row = c >> 4, col = c & 15;
                if (rowbase + row < Nn)
                    *(uint4*)&hb[((size_t)(rowbase + row)) * DH + col * 8] = *(uint4*)&Bs[row][col * 8];
            }
        }
    }
}

// ---------- pass-1 aggregation: one wave per dst, fp8 gather, 2 edges/step x8 ----------
// hbf[dst] = bf16( hb[dst] + (1/deg) * sum_e xw8[type_e][src_e] )
__global__ __launch_bounds__(256) void k_agg1(const int* __restrict__ offsets,
                                              const unsigned* __restrict__ sorted,
                                              const unsigned* __restrict__ xw8,
                                              const unsigned* __restrict__ hb32,
                                              int Nn, unsigned* __restrict__ hbf) {
    int w = (blockIdx.x * blockDim.x + threadIdx.x) >> 6;
    if (w >= Nn) return;
    int lane = threadIdx.x & 63;
    int half = lane >> 5, sub = lane & 31;    // half-wave h reads edge 2j+h, 4 features/lane
    int s = offsets[w], e = offsets[w + 1];
    float a0 = 0.f, a1 = 0.f, a2 = 0.f, a3 = 0.f;
    int p = s;
    for (; p + 16 <= e; p += 16) {            // unmasked main loop
        unsigned pk[8];
        #pragma unroll
        for (int j = 0; j < 8; ++j) pk[j] = sorted[p + 2 * j + half];
        unsigned u[8];
        #pragma unroll
        for (int j = 0; j < 8; ++j)
            u[j] = xw8[((size_t)(pk[j] >> 17) * Nn + (pk[j] & 0x1FFFFu)) * 32 + sub];
        #pragma unroll
        for (int j = 0; j < 8; ++j) {
            f32x2 lo = __builtin_amdgcn_cvt_pk_f32_fp8(u[j], false);
            f32x2 hi = __builtin_amdgcn_cvt_pk_f32_fp8(u[j], true);
            a0 += lo.x; a1 += lo.y; a2 += hi.x; a3 += hi.y;
        }
    }
    if (p < e) {                              // masked tail
        unsigned pk[8]; float m[8];
        #pragma unroll
        for (int j = 0; j < 8; ++j) {
            int q = p + 2 * j + half; bool v = q < e;
            pk[j] = sorted[v ? q : e - 1];
            m[j] = v ? 1.f : 0.f;
        }
        unsigned u[8];
        #pragma unroll
        for (int j = 0; j < 8; ++j)
            u[j] = xw8[((size_t)(pk[j] >> 17) * Nn + (pk[j] & 0x1FFFFu)) * 32 + sub];
        #pragma unroll
        for (int j = 0; j < 8; ++j) {
            f32x2 lo = __builtin_amdgcn_cvt_pk_f32_fp8(u[j], false);
            f32x2 hi = __builtin_amdgcn_cvt_pk_f32_fp8(u[j], true);
            a0 = fmaf(m[j], lo.x, a0);
            a1 = fmaf(m[j], lo.y, a1);
            a2 = fmaf(m[j], hi.x, a2);
            a3 = fmaf(m[j], hi.y, a3);
        }
    }
    a0 += __shfl_xor(a0, 32, 64);
    a1 += __shfl_xor(a1, 32, 64);
    a2 += __shfl_xor(a2, 32, 64);
    a3 += __shfl_xor(a3, 32, 64);
    if (half == 0) {
        float invd = 1.0f / fmaxf((float)(e - s), 1.0f);
        uint2 hv = *(const uint2*)&hb32[(size_t)w * 64 + sub * 2];
        float h0 = bflo(hv.x) + a0 * invd;
        float h1 = bfhi(hv.x) + a1 * invd;
        float h2 = bflo(hv.y) + a2 * invd;
        float h3 = bfhi(hv.y) + a3 * invd;
        uint2 o;
        o.x = (unsigned)f2bf(h0) | ((unsigned)f2bf(h1) << 16);
        o.y = (unsigned)f2bf(h2) | ((unsigned)f2bf(h3) << 16);
        *(uint2*)&hbf[(size_t)w * 64 + sub * 2] = o;
    }
}

// ---------- pass-2 aggregation: half-wave uint2 bf16 gather, 2 edges/step x8 ----------
// nbrbf[dst] = bf16( sum_e h[src_e] )
__global__ __launch_bounds__(256) void k_agg2(const int* __restrict__ offsets,
                                              const unsigned* __restrict__ sorted,
                                              const uint2* __restrict__ hbf2,   // 32 uint2 per row
                                              int Nn, uint2* __restrict__ nbr2) {
    int w = (blockIdx.x * blockDim.x + threadIdx.x) >> 6;
    if (w >= Nn) return;
    int lane = threadIdx.x & 63;
    int half = lane >> 5, sub = lane & 31;    // features [4*sub, 4*sub+4)
    int s = offsets[w], e = offsets[w + 1];
    float a0 = 0.f, a1 = 0.f, a2 = 0.f, a3 = 0.f;
    int p = s;
    for (; p + 16 <= e; p += 16) {            // unmasked main loop
        unsigned pk[8];
        #pragma unroll
        for (int j = 0; j < 8; ++j) pk[j] = sorted[p + 2 * j + half];
        uint2 u[8];
        #pragma unroll
        for (int j = 0; j < 8; ++j)
            u[j] = hbf2[(size_t)(pk[j] & 0x1FFFFu) * 32 + sub];
        #pragma unroll
        for (int j = 0; j < 8; ++j) {
            a0 += bflo(u[j].x); a1 += bfhi(u[j].x);
            a2 += bflo(u[j].y); a3 += bfhi(u[j].y);
        }
    }
    if (p < e) {                              // masked tail
        unsigned pk[8]; float m[8];
        #pragma unroll
        for (int j = 0; j < 8; ++j) {
            int q = p + 2 * j + half; bool v = q < e;
            pk[j] = sorted[v ? q : e - 1];
            m[j] = v ? 1.f : 0.f;
        }
        uint2 u[8];
        #pragma unroll
        for (int j = 0; j < 8; ++j)
            u[j] = hbf2[(size_t)(pk[j] & 0x1FFFFu) * 32 + sub];
        #pragma unroll
        for (int j = 0; j < 8; ++j) {
            a0 = fmaf(m[j], bflo(u[j].x), a0);
            a1 = fmaf(m[j], bfhi(u[j].x), a1);
            a2 = fmaf(m[j], bflo(u[j].y), a2);
            a3 = fmaf(m[j], bfhi(u[j].y), a3);
        }
    }
    a0 += __shfl_xor(a0, 32, 64);
    a1 += __shfl_xor(a1, 32, 64);
    a2 += __shfl_xor(a2, 32, 64);
    a3 += __shfl_xor(a3, 32, 64);
    if (half == 0) {
        uint2 o;
        o.x = (unsigned)f2bf(a0) | ((unsigned)f2bf(a1) << 16);
        o.y = (unsigned)f2bf(a2) | ((unsigned)f2bf(a3) << 16);
        nbr2[(size_t)w * 32 + sub] = o;
    }
}

// ---------- MFMA GEMM2: out = nbr@w_rel + h@w_root2 + bias2 (K=256 in 2 phases) ----------
__global__ __launch_bounds__(256) void k_gemm2m(const unsigned short* __restrict__ nbrbf,
                                                const unsigned short* __restrict__ hbf,
                                                const unsigned short* __restrict__ WT2,
                                                const float* __restrict__ bias2,
                                                int Nn, float* __restrict__ out) {
    __shared__ __align__(16) unsigned short As[128][136];
    __shared__ __align__(16) unsigned short Bs[128][136];
    const int tid = threadIdx.x;
    const int wave = tid >> 6, lane = tid & 63;
    const int rowbase = blockIdx.x * 128;
    const int lq = lane >> 4, lr = lane & 15;

    f32x4 acc[2][8];
    #pragma unroll
    for (int mt = 0; mt < 2; ++mt)
        #pragma unroll
        for (int nt = 0; nt < 8; ++nt) acc[mt][nt] = (f32x4)0.f;

    for (int ph = 0; ph < 2; ++ph) {
        const unsigned short* A = ph ? hbf : nbrbf;
        const unsigned short* WT = WT2 + (size_t)ph * DH * DH;
        if (ph) __syncthreads();
        #pragma unroll
        for (int it = 0; it < 8; ++it) {
            int c = it * 256 + tid;
            int row = c >> 4, col = c & 15;
            int rg = rowbase + row; if (rg >= Nn) rg = Nn - 1;
            *(uint4*)&As[row][col * 8] = *(const uint4*)&A[(size_t)rg * DH + col * 8];
            *(uint4*)&Bs[row][col * 8] = *(const uint4*)&WT[(size_t)row * DH + col * 8];
        }
        __syncthreads();
        #pragma unroll
        for (int ks = 0; ks < 4; ++ks) {
            const int ko = ks * 32 + lq * 8;
            bf16x8 a0 = *(const bf16x8*)&As[wave * 32 + lr][ko];
            bf16x8 a1 = *(const bf16x8*)&As[wave * 32 + 16 + lr][ko];
            #pragma unroll
            for (int nt = 0; nt < 8; ++nt) {
                bf16x8 b = *(const bf16x8*)&Bs[nt * 16 + lr][ko];
                acc[0][nt] = __builtin_amdgcn_mfma_f32_16x16x32_bf16(a0, b, acc[0][nt], 0, 0, 0);
                acc[1][nt] = __builtin_amdgcn_mfma_f32_16x16x32_bf16(a1, b, acc[1][nt], 0, 0, 0);
            }
        }
    }

    float bv[8];
    #pragma unroll
    for (int nt = 0; nt < 8; ++nt) bv[nt] = bias2[nt * 16 + lr];
    #pragma unroll
    for (int mt = 0; mt < 2; ++mt)
        #pragma unroll
        for (int nt = 0; nt < 8; ++nt)
            #pragma unroll
            for (int reg = 0; reg < 4; ++reg) {
                int m = rowbase + wave * 32 + mt * 16 + lq * 4 + reg;
                if (m < Nn) out[(size_t)m * DH + nt * 16 + lr] = acc[mt][nt][reg] + bv[nt];
            }
}

extern "C" void kernel_launch(void* const* d_in, const int* in_sizes, int n_in,
                              void* d_out, int out_size, void* d_ws, size_t ws_size,
                              hipStream_t stream) {
    const float* x      = (const float*)d_in[0];
    const int*   eidx   = (const int*)d_in[1];
    // d_in[2] = edge_norm: unused by the reference computation
    const int*   etype  = (const int*)d_in[3];
    const float* basis  = (const float*)d_in[4];
    const float* comp   = (const float*)d_in[5];
    const float* root   = (const float*)d_in[6];
    const float* bias1  = (const float*)d_in[7];
    const float* wrel   = (const float*)d_in[8];
    const float* wroot2 = (const float*)d_in[9];
    const float* bias2  = (const float*)d_in[10];
    float* out = (float*)d_out;

    const int N = in_sizes[0] / DH;    // 40000
    const int E = in_sizes[3];         // 640000
    const int* srcA = eidx;
    const int* dstA = eidx + E;

    char* ws = (char*)d_ws;
    size_t off = 0;
    auto alloc = [&](size_t bytes) -> void* {
        void* p = (void*)(ws + off);
        off += (bytes + 255) & ~(size_t)255;
        return p;
    };
    // deg, cursor, scan-state, ticket are contiguous and zeroed by one memset
    int* deg           = (int*)alloc((size_t)N * 4);          // N*4 multiple of 256
    int* cursor        = (int*)alloc((size_t)N * 4);
    unsigned long long* st = (unsigned long long*)alloc(64 * 8);   // 512 B
    int* ticket        = (int*)alloc(256);
    int* offsets       = (int*)alloc((size_t)(N + 1) * 4);
    unsigned* sorted   = (unsigned*)alloc((size_t)E * 4);
    unsigned short* wallT = (unsigned short*)alloc((size_t)(NR + 1) * DH * DH * 2);
    unsigned short* WT2   = (unsigned short*)alloc((size_t)2 * DH * DH * 2);
    unsigned* xw8      = (unsigned*)alloc((size_t)NR * N * DH);       // fp8 e4m3
    unsigned short* hb = (unsigned short*)alloc((size_t)N * DH * 2);
    unsigned* hbf      = (unsigned*)alloc((size_t)N * (DH / 2) * 4);
    unsigned* nbrbf    = (unsigned*)alloc((size_t)N * (DH / 2) * 4);
    (void)ws_size; (void)n_in; (void)out_size;

    hipMemsetAsync(deg, 0, (size_t)N * 8 + 768, stream);  // deg+cursor+st+ticket

    const int histB = (E + 255) / 256;              // 2500
    k_prephist<<<histB + 704, 256, 0, stream>>>(comp, basis, root, wrel, wroot2,
                                                wallT, WT2, dstA, E, deg, histB);

    const int totn = N + 1;
    const int nsb = (totn + 1023) / 1024;           // 40
    k_scan<<<nsb, 1024, 0, stream>>>(deg, N, totn, offsets, st, ticket);
    k_scatter<<<(E + 255) / 256, 256, 0, stream>>>(srcA, dstA, etype, E, offsets, cursor, sorted);

    const int gx = (N + 127) / 128;
    k_gemm1m<<<dim3(gx, 3), 256, 0, stream>>>(x, wallT, bias1, N, xw8, hb);
    k_agg1<<<(N * 64) / 256, 256, 0, stream>>>(offsets, sorted, xw8,
                                               (const unsigned*)hb, N, hbf);
    k_agg2<<<(N * 64) / 256, 256, 0, stream>>>(offsets, sorted, (const uint2*)hbf, N, (uint2*)nbrbf);
    k_gemm2m<<<gx, 256, 0, stream>>>((const unsigned short*)nbrbf, (const unsigned short*)hbf,
                                     WT2, bias2, N, out);
}

// Round 12
// 241.088 us; speedup vs baseline: 1.4250x; 1.0086x over previous
//
#include <hip/hip_runtime.h>
#include <stdint.h>

#define DH 128   // D_IN == H == 128
#define NB 30    // num bases
#define NR 8     // num relations

typedef short bf16x8 __attribute__((ext_vector_type(8)));   // 8 bf16 = 4 VGPRs
typedef float f32x4 __attribute__((ext_vector_type(4)));
typedef float f32x2 __attribute__((ext_vector_type(2)));

static __device__ __forceinline__ unsigned short f2bf(float f) {
    unsigned u = __float_as_uint(f);
    u += 0x7fffu + ((u >> 16) & 1u);   // round-to-nearest-even
    return (unsigned short)(u >> 16);
}
static __device__ __forceinline__ float bflo(unsigned u) { return __uint_as_float(u << 16); }
static __device__ __forceinline__ float bfhi(unsigned u) { return __uint_as_float(u & 0xffff0000u); }

// ---------- merged weight-prep + edge histogram ----------
__global__ __launch_bounds__(256) void k_prephist(const float* __restrict__ comp,
                                                  const float* __restrict__ basis,
                                                  const float* __restrict__ root,
                                                  const float* __restrict__ wrel,
                                                  const float* __restrict__ wroot2,
                                                  unsigned short* __restrict__ wallT,
                                                  unsigned short* __restrict__ WT2,
                                                  const int* __restrict__ dstA, int E,
                                                  int* __restrict__ deg, int histB) {
    int b = blockIdx.x;
    int tid = threadIdx.x;
    if (b < histB) {
        int e = b * 256 + tid;
        if (e < E) atomicAdd(&deg[dstA[e]], 1);
        return;
    }
    int unit = (b - histB) * 2 + (tid >> 7);   // 0..1407 = y*128 + i
    int o = tid & 127;
    int i = unit & 127;
    int y = unit >> 7;                          // 0..10
    if (y < NR) {
        float s = 0.f;
        #pragma unroll
        for (int bb = 0; bb < NB; ++bb)
            s += comp[y * NB + bb] * basis[((size_t)bb * DH + i) * DH + o];
        wallT[((size_t)y * DH + o) * DH + i] = f2bf(s);
    } else if (y == NR) {
        wallT[((size_t)NR * DH + o) * DH + i] = f2bf(root[i * DH + o]);
    } else {
        const float* W = (y == NR + 2) ? wroot2 : wrel;
        WT2[((size_t)(y - NR - 1) * DH + o) * DH + i] = f2bf(W[i * DH + o]);
    }
}

// ---------- single-pass scan (ticket-ordered decoupled lookback) ----------
// Also pre-initializes cursor[i] = offsets[i] for the scatter phase.
__global__ __launch_bounds__(1024) void k_scan(const int* __restrict__ deg, int n, int total_n,
                                               int* __restrict__ offsets,
                                               int* __restrict__ cursor,
                                               unsigned long long* __restrict__ st,
                                               int* __restrict__ ticket) {
    __shared__ int s[1024];
    __shared__ int bid_s, pre_s;
    const int tid = threadIdx.x;
    if (tid == 0) bid_s = atomicAdd(ticket, 1);
    __syncthreads();
    const int b = bid_s;
    int i = b * 1024 + tid;
    int v = (i < n) ? deg[i] : 0;
    s[tid] = v;
    __syncthreads();
    for (int off = 1; off < 1024; off <<= 1) {
        int t = (tid >= off) ? s[tid - off] : 0;
        __syncthreads();
        s[tid] += t;
        __syncthreads();
    }
    if (tid == 0) {
        int total = s[1023];
        atomicExch(&st[b], (1ULL << 62) | (unsigned long long)(unsigned)total);
        long long pre = 0;
        int t = b - 1;
        while (t >= 0) {
            unsigned long long w;
            do { w = atomicAdd(&st[t], 0ULL); } while (w == 0ULL);
            pre += (long long)(w & 0x3FFFFFFFFFFFFFFFULL);
            if ((w >> 62) == 2ULL) break;
            --t;
        }
        atomicExch(&st[b], (2ULL << 62) | (unsigned long long)(pre + total));
        pre_s = (int)pre;
    }
    __syncthreads();
    int ov = pre_s + s[tid] - v;   // exclusive
    if (i < total_n) offsets[i] = ov;
    if (i < n) cursor[i] = ov;
}

// ---------- fused MFMA GEMM1 + scatter (role-partitioned) ----------
// blocks [0, gemmB): gemm tiles (b%gx = tile, b/gx = relation group g, r = 3g..3g+2)
//   r<8: xw8[r] = fp8(X @ W_r). r==8: hb = bf16(X @ root + bias1)
// blocks [gemmB, gridDim): grid-stride CSR scatter using pre-initialized cursor.
__global__ __launch_bounds__(256) void k_gemm1s(const float* __restrict__ x,
                                                const unsigned short* __restrict__ wallT,
                                                const float* __restrict__ bias1,
                                                int Nn,
                                                unsigned* __restrict__ xw8,
                                                unsigned short* __restrict__ hb,
                                                const int* __restrict__ src,
                                                const int* __restrict__ dstA,
                                                const int* __restrict__ etype, int E,
                                                int* __restrict__ cursor,
                                                unsigned* __restrict__ sorted,
                                                int gemmB, int gx) {
    __shared__ __align__(16) unsigned short As[128][136];  // [m][k], +8 pad
    __shared__ __align__(16) unsigned short Bs[128][136];  // [n][k] / epilogue repack
    const int tid = threadIdx.x;
    const int b = blockIdx.x;

    if (b >= gemmB) {                     // ---- scatter role ----
        const int stride = (gridDim.x - gemmB) * 256;
        for (int e = (b - gemmB) * 256 + tid; e < E; e += stride) {
            int d = dstA[e];
            int pos = atomicAdd(&cursor[d], 1);
            sorted[pos] = (unsigned)src[e] | ((unsigned)etype[e] << 17);  // src<2^17, type<8
        }
        return;
    }

    const int wave = tid >> 6, lane = tid & 63;
    const int g = b / gx;
    const int rowbase = (b % gx) * 128;
    const int lq = lane >> 4, lr = lane & 15;

    // stage A once: fp32 -> bf16 on the fly
    #pragma unroll
    for (int it = 0; it < 8; ++it) {
        int c = it * 256 + tid;
        int row = c >> 4, col = c & 15;
        int rg = rowbase + row; if (rg >= Nn) rg = Nn - 1;
        float4 v0 = *(const float4*)&x[(size_t)rg * DH + col * 8];
        float4 v1 = *(const float4*)&x[(size_t)rg * DH + col * 8 + 4];
        uint4 u;
        u.x = (unsigned)f2bf(v0.x) | ((unsigned)f2bf(v0.y) << 16);
        u.y = (unsigned)f2bf(v0.z) | ((unsigned)f2bf(v0.w) << 16);
        u.z = (unsigned)f2bf(v1.x) | ((unsigned)f2bf(v1.y) << 16);
        u.w = (unsigned)f2bf(v1.z) | ((unsigned)f2bf(v1.w) << 16);
        *(uint4*)&As[row][col * 8] = u;
    }

    for (int rr = 0; rr < 3; ++rr) {
        const int r = g * 3 + rr;
        const unsigned short* WT = wallT + (size_t)r * DH * DH;
        if (rr) __syncthreads();            // prior epilogue reads of Bs done
        #pragma unroll
        for (int it = 0; it < 8; ++it) {
            int c = it * 256 + tid;
            int row = c >> 4, col = c & 15;
            *(uint4*)&Bs[row][col * 8] = *(const uint4*)&WT[(size_t)row * DH + col * 8];
        }
        __syncthreads();                    // also covers As on first iter

        f32x4 acc[2][8];
        #pragma unroll
        for (int mt = 0; mt < 2; ++mt)
            #pragma unroll
            for (int nt = 0; nt < 8; ++nt) acc[mt][nt] = (f32x4)0.f;

        #pragma unroll
        for (int ks = 0; ks < 4; ++ks) {
            const int ko = ks * 32 + lq * 8;
            bf16x8 a0 = *(const bf16x8*)&As[wave * 32 + lr][ko];
            bf16x8 a1 = *(const bf16x8*)&As[wave * 32 + 16 + lr][ko];
            #pragma unroll
            for (int nt = 0; nt < 8; ++nt) {
                bf16x8 bb = *(const bf16x8*)&Bs[nt * 16 + lr][ko];
                acc[0][nt] = __builtin_amdgcn_mfma_f32_16x16x32_bf16(a0, bb, acc[0][nt], 0, 0, 0);
                acc[1][nt] = __builtin_amdgcn_mfma_f32_16x16x32_bf16(a1, bb, acc[1][nt], 0, 0, 0);
            }
        }
        __syncthreads();                    // all MFMA reads of Bs done

        // repack C-layout -> canonical bf16 rows in Bs
        float bv[8];
        #pragma unroll
        for (int nt = 0; nt < 8; ++nt) bv[nt] = (r == NR) ? bias1[nt * 16 + lr] : 0.f;
        #pragma unroll
        for (int mt = 0; mt < 2; ++mt)
            #pragma unroll
            for (int nt = 0; nt < 8; ++nt)
                #pragma unroll
                for (int reg = 0; reg < 4; ++reg) {
                    int ml = wave * 32 + mt * 16 + lq * 4 + reg;   // own slab only
                    Bs[ml][nt * 16 + lr] = f2bf(acc[mt][nt][reg] + bv[nt]);
                }
        __syncthreads();

        if (r < NR) {
            unsigned* dst = xw8 + ((size_t)r * Nn + rowbase) * (DH / 4);
            #pragma unroll
            for (int it = 0; it < 8; ++it) {
                int c = it * 256 + tid;
                int row = c >> 4, col = c & 15;
                if (rowbase + row < Nn) {
                    uint4 q = *(uint4*)&Bs[row][col * 8];
                    uint2 o;
                    o.x = __builtin_amdgcn_cvt_pk_fp8_f32(bflo(q.x), bfhi(q.x), 0, false);
                    o.x = __builtin_amdgcn_cvt_pk_fp8_f32(bflo(q.y), bfhi(q.y), o.x, true);
                    o.y = __builtin_amdgcn_cvt_pk_fp8_f32(bflo(q.z), bfhi(q.z), 0, false);
                    o.y = __builtin_amdgcn_cvt_pk_fp8_f32(bflo(q.w), bfhi(q.w), o.y, true);
                    *(uint2*)&dst[(size_t)row * (DH / 4) + col * 2] = o;
                }
            }
        } else {
            #pragma unroll
            for (int it = 0; it < 8; ++it) {
                int c = it * 256 + tid;
                int row = c >> 4, col = c & 15;
                if (rowbase + row < Nn)
                    *(uint4*)&hb[((size_t)(rowbase + row)) * DH + col * 8] = *(uint4*)&Bs[row][col * 8];
            }
        }
    }
}

// ---------- pass-1 aggregation: one wave per dst, fp8 gather, 2 edges/step x8 ----------
// hbf[dst] = bf16( hb[dst] + (1/deg) * sum_e xw8[type_e][src_e] )
__global__ __launch_bounds__(256) void k_agg1(const int* __restrict__ offsets,
                                              const unsigned* __restrict__ sorted,
                                              const unsigned* __restrict__ xw8,
                                              const unsigned* __restrict__ hb32,
                                              int Nn, unsigned* __restrict__ hbf) {
    int w = (blockIdx.x * blockDim.x + threadIdx.x) >> 6;
    if (w >= Nn) return;
    int lane = threadIdx.x & 63;
    int half = lane >> 5, sub = lane & 31;
    int s = offsets[w], e = offsets[w + 1];
    float a0 = 0.f, a1 = 0.f, a2 = 0.f, a3 = 0.f;
    int p = s;
    for (; p + 16 <= e; p += 16) {            // unmasked main loop
        unsigned pk[8];
        #pragma unroll
        for (int j = 0; j < 8; ++j) pk[j] = sorted[p + 2 * j + half];
        unsigned u[8];
        #pragma unroll
        for (int j = 0; j < 8; ++j)
            u[j] = xw8[((size_t)(pk[j] >> 17) * Nn + (pk[j] & 0x1FFFFu)) * 32 + sub];
        #pragma unroll
        for (int j = 0; j < 8; ++j) {
            f32x2 lo = __builtin_amdgcn_cvt_pk_f32_fp8(u[j], false);
            f32x2 hi = __builtin_amdgcn_cvt_pk_f32_fp8(u[j], true);
            a0 += lo.x; a1 += lo.y; a2 += hi.x; a3 += hi.y;
        }
    }
    if (p < e) {                              // masked tail
        unsigned pk[8]; float m[8];
        #pragma unroll
        for (int j = 0; j < 8; ++j) {
            int q = p + 2 * j + half; bool v = q < e;
            pk[j] = sorted[v ? q : e - 1];
            m[j] = v ? 1.f : 0.f;
        }
        unsigned u[8];
        #pragma unroll
        for (int j = 0; j < 8; ++j)
            u[j] = xw8[((size_t)(pk[j] >> 17) * Nn + (pk[j] & 0x1FFFFu)) * 32 + sub];
        #pragma unroll
        for (int j = 0; j < 8; ++j) {
            f32x2 lo = __builtin_amdgcn_cvt_pk_f32_fp8(u[j], false);
            f32x2 hi = __builtin_amdgcn_cvt_pk_f32_fp8(u[j], true);
            a0 = fmaf(m[j], lo.x, a0);
            a1 = fmaf(m[j], lo.y, a1);
            a2 = fmaf(m[j], hi.x, a2);
            a3 = fmaf(m[j], hi.y, a3);
        }
    }
    a0 += __shfl_xor(a0, 32, 64);
    a1 += __shfl_xor(a1, 32, 64);
    a2 += __shfl_xor(a2, 32, 64);
    a3 += __shfl_xor(a3, 32, 64);
    if (half == 0) {
        float invd = 1.0f / fmaxf((float)(e - s), 1.0f);
        uint2 hv = *(const uint2*)&hb32[(size_t)w * 64 + sub * 2];
        float h0 = bflo(hv.x) + a0 * invd;
        float h1 = bfhi(hv.x) + a1 * invd;
        float h2 = bflo(hv.y) + a2 * invd;
        float h3 = bfhi(hv.y) + a3 * invd;
        uint2 o;
        o.x = (unsigned)f2bf(h0) | ((unsigned)f2bf(h1) << 16);
        o.y = (unsigned)f2bf(h2) | ((unsigned)f2bf(h3) << 16);
        *(uint2*)&hbf[(size_t)w * 64 + sub * 2] = o;
    }
}

// ---------- pass-2 aggregation: half-wave uint2 bf16 gather ----------
__global__ __launch_bounds__(256) void k_agg2(const int* __restrict__ offsets,
                                              const unsigned* __restrict__ sorted,
                                              const uint2* __restrict__ hbf2,
                                              int Nn, uint2* __restrict__ nbr2) {
    int w = (blockIdx.x * blockDim.x + threadIdx.x) >> 6;
    if (w >= Nn) return;
    int lane = threadIdx.x & 63;
    int half = lane >> 5, sub = lane & 31;
    int s = offsets[w], e = offsets[w + 1];
    float a0 = 0.f, a1 = 0.f, a2 = 0.f, a3 = 0.f;
    int p = s;
    for (; p + 16 <= e; p += 16) {
        unsigned pk[8];
        #pragma unroll
        for (int j = 0; j < 8; ++j) pk[j] = sorted[p + 2 * j + half];
        uint2 u[8];
        #pragma unroll
        for (int j = 0; j < 8; ++j)
            u[j] = hbf2[(size_t)(pk[j] & 0x1FFFFu) * 32 + sub];
        #pragma unroll
        for (int j = 0; j < 8; ++j) {
            a0 += bflo(u[j].x); a1 += bfhi(u[j].x);
            a2 += bflo(u[j].y); a3 += bfhi(u[j].y);
        }
    }
    if (p < e) {
        unsigned pk[8]; float m[8];
        #pragma unroll
        for (int j = 0; j < 8; ++j) {
            int q = p + 2 * j + half; bool v = q < e;
            pk[j] = sorted[v ? q : e - 1];
            m[j] = v ? 1.f : 0.f;
        }
        uint2 u[8];
        #pragma unroll
        for (int j = 0; j < 8; ++j)
            u[j] = hbf2[(size_t)(pk[j] & 0x1FFFFu) * 32 + sub];
        #pragma unroll
        for (int j = 0; j < 8; ++j) {
            a0 = fmaf(m[j], bflo(u[j].x), a0);
            a1 = fmaf(m[j], bfhi(u[j].x), a1);
            a2 = fmaf(m[j], bflo(u[j].y), a2);
            a3 = fmaf(m[j], bfhi(u[j].y), a3);
        }
    }
    a0 += __shfl_xor(a0, 32, 64);
    a1 += __shfl_xor(a1, 32, 64);
    a2 += __shfl_xor(a2, 32, 64);
    a3 += __shfl_xor(a3, 32, 64);
    if (half == 0) {
        uint2 o;
        o.x = (unsigned)f2bf(a0) | ((unsigned)f2bf(a1) << 16);
        o.y = (unsigned)f2bf(a2) | ((unsigned)f2bf(a3) << 16);
        nbr2[(size_t)w * 32 + sub] = o;
    }
}

// ---------- MFMA GEMM2: out = nbr@w_rel + h@w_root2 + bias2 (K=256 in 2 phases) ----------
__global__ __launch_bounds__(256) void k_gemm2m(const unsigned short* __restrict__ nbrbf,
                                                const unsigned short* __restrict__ hbf,
                                                const unsigned short* __restrict__ WT2,
                                                const float* __restrict__ bias2,
                                                int Nn, float* __restrict__ out) {
    __shared__ __align__(16) unsigned short As[128][136];
    __shared__ __align__(16) unsigned short Bs[128][136];
    const int tid = threadIdx.x;
    const int wave = tid >> 6, lane = tid & 63;
    const int rowbase = blockIdx.x * 128;
    const int lq = lane >> 4, lr = lane & 15;

    f32x4 acc[2][8];
    #pragma unroll
    for (int mt = 0; mt < 2; ++mt)
        #pragma unroll
        for (int nt = 0; nt < 8; ++nt) acc[mt][nt] = (f32x4)0.f;

    for (int ph = 0; ph < 2; ++ph) {
        const unsigned short* A = ph ? hbf : nbrbf;
        const unsigned short* WT = WT2 + (size_t)ph * DH * DH;
        if (ph) __syncthreads();
        #pragma unroll
        for (int it = 0; it < 8; ++it) {
            int c = it * 256 + tid;
            int row = c >> 4, col = c & 15;
            int rg = rowbase + row; if (rg >= Nn) rg = Nn - 1;
            *(uint4*)&As[row][col * 8] = *(const uint4*)&A[(size_t)rg * DH + col * 8];
            *(uint4*)&Bs[row][col * 8] = *(const uint4*)&WT[(size_t)row * DH + col * 8];
        }
        __syncthreads();
        #pragma unroll
        for (int ks = 0; ks < 4; ++ks) {
            const int ko = ks * 32 + lq * 8;
            bf16x8 a0 = *(const bf16x8*)&As[wave * 32 + lr][ko];
            bf16x8 a1 = *(const bf16x8*)&As[wave * 32 + 16 + lr][ko];
            #pragma unroll
            for (int nt = 0; nt < 8; ++nt) {
                bf16x8 b = *(const bf16x8*)&Bs[nt * 16 + lr][ko];
                acc[0][nt] = __builtin_amdgcn_mfma_f32_16x16x32_bf16(a0, b, acc[0][nt], 0, 0, 0);
                acc[1][nt] = __builtin_amdgcn_mfma_f32_16x16x32_bf16(a1, b, acc[1][nt], 0, 0, 0);
            }
        }
    }

    float bv[8];
    #pragma unroll
    for (int nt = 0; nt < 8; ++nt) bv[nt] = bias2[nt * 16 + lr];
    #pragma unroll
    for (int mt = 0; mt < 2; ++mt)
        #pragma unroll
        for (int nt = 0; nt < 8; ++nt)
            #pragma unroll
            for (int reg = 0; reg < 4; ++reg) {
                int m = rowbase + wave * 32 + mt * 16 + lq * 4 + reg;
                if (m < Nn) out[(size_t)m * DH + nt * 16 + lr] = acc[mt][nt][reg] + bv[nt];
            }
}

extern "C" void kernel_launch(void* const* d_in, const int* in_sizes, int n_in,
                              void* d_out, int out_size, void* d_ws, size_t ws_size,
                              hipStream_t stream) {
    const float* x      = (const float*)d_in[0];
    const int*   eidx   = (const int*)d_in[1];
    // d_in[2] = edge_norm: unused by the reference computation
    const int*   etype  = (const int*)d_in[3];
    const float* basis  = (const float*)d_in[4];
    const float* comp   = (const float*)d_in[5];
    const float* root   = (const float*)d_in[6];
    const float* bias1  = (const float*)d_in[7];
    const float* wrel   = (const float*)d_in[8];
    const float* wroot2 = (const float*)d_in[9];
    const float* bias2  = (const float*)d_in[10];
    float* out = (float*)d_out;

    const int N = in_sizes[0] / DH;    // 40000
    const int E = in_sizes[3];         // 640000
    const int* srcA = eidx;
    const int* dstA = eidx + E;

    char* ws = (char*)d_ws;
    size_t off = 0;
    auto alloc = [&](size_t bytes) -> void* {
        void* p = (void*)(ws + off);
        off += (bytes + 255) & ~(size_t)255;
        return p;
    };
    // deg, st, ticket contiguous -> zeroed by one memset (cursor now written by k_scan)
    int* deg           = (int*)alloc((size_t)N * 4);          // N*4 multiple of 256
    unsigned long long* st = (unsigned long long*)alloc(64 * 8);   // 512 B
    int* ticket        = (int*)alloc(256);
    int* cursor        = (int*)alloc((size_t)N * 4);
    int* offsets       = (int*)alloc((size_t)(N + 1) * 4);
    unsigned* sorted   = (unsigned*)alloc((size_t)E * 4);
    unsigned short* wallT = (unsigned short*)alloc((size_t)(NR + 1) * DH * DH * 2);
    unsigned short* WT2   = (unsigned short*)alloc((size_t)2 * DH * DH * 2);
    unsigned* xw8      = (unsigned*)alloc((size_t)NR * N * DH);       // fp8 e4m3
    unsigned short* hb = (unsigned short*)alloc((size_t)N * DH * 2);
    unsigned* hbf      = (unsigned*)alloc((size_t)N * (DH / 2) * 4);
    unsigned* nbrbf    = (unsigned*)alloc((size_t)N * (DH / 2) * 4);
    (void)ws_size; (void)n_in; (void)out_size;

    hipMemsetAsync(deg, 0, (size_t)N * 4 + 768, stream);  // deg + st + ticket

    const int histB = (E + 255) / 256;              // 2500
    k_prephist<<<histB + 704, 256, 0, stream>>>(comp, basis, root, wrel, wroot2,
                                                wallT, WT2, dstA, E, deg, histB);

    const int totn = N + 1;
    const int nsb = (totn + 1023) / 1024;           // 40
    k_scan<<<nsb, 1024, 0, stream>>>(deg, N, totn, offsets, cursor, st, ticket);

    const int gx = (N + 127) / 128;                 // 313
    const int gemmB = gx * 3;                       // 939
    const int scatB = 1280;                         // grid-stride scatter blocks
    k_gemm1s<<<gemmB + scatB, 256, 0, stream>>>(x, wallT, bias1, N, xw8, hb,
                                                srcA, dstA, etype, E, cursor, sorted,
                                                gemmB, gx);

    k_agg1<<<(N * 64) / 256, 256, 0, stream>>>(offsets, sorted, xw8,
                                               (const unsigned*)hb, N, hbf);
    k_agg2<<<(N * 64) / 256, 256, 0, stream>>>(offsets, sorted, (const uint2*)hbf, N, (uint2*)nbrbf);
    k_gemm2m<<<gx, 256, 0, stream>>>((const unsigned short*)nbrbf, (const unsigned short*)hbf,
                                     WT2, bias2, N, out);
}